// Round 1
// baseline (2218.849 us; speedup 1.0000x reference)
//
#include <hip/hip_runtime.h>

#define BB 2
#define CC 512
#define NH 8
#define DDIM 64
#define NN 4096
#define SCALE 0.125f

// ---------------- QKV GEMM ----------------
// q/k/v each stored [B][NH][DDIM][NN] (channel-major) in workspace.
__global__ __launch_bounds__(256)
void qkv_kernel(const float* __restrict__ x, const float* __restrict__ W,
                const float* __restrict__ bias, float* __restrict__ q,
                float* __restrict__ k, float* __restrict__ v) {
    const int nt = blockIdx.x;      // 64 n-tiles
    const int ot = blockIdx.y;      // 24 o-tiles
    const int b  = blockIdx.z;
    const int t  = threadIdx.x;
    const int o0 = ot * 64;
    const int n0 = nt * 64;

    __shared__ float As[32][65];  // [k][m] (transposed store, padded)
    __shared__ float Bs[32][68];  // [k][j] (float4 rows, 68 keeps 16B align)

    const int tm = t / 16;
    const int tn = t % 16;

    float acc[4][4];
    #pragma unroll
    for (int i=0;i<4;i++)
        #pragma unroll
        for (int j=0;j<4;j++) acc[i][j]=0.f;

    for (int k0 = 0; k0 < CC; k0 += 32) {
        {   // W tile 64(o) x 32(c)
            int row = t / 8;          // 0..31
            int cg  = t % 8;          // 0..7
            #pragma unroll
            for (int r=0;r<2;r++) {
                int m = row + r*32;
                const float4 w4 = *(const float4*)(&W[(size_t)(o0+m)*CC + k0 + cg*4]);
                As[cg*4+0][m] = w4.x;
                As[cg*4+1][m] = w4.y;
                As[cg*4+2][m] = w4.z;
                As[cg*4+3][m] = w4.w;
            }
        }
        {   // x tile 32(c) x 64(n)
            int row = t / 16;  // 0..15 (x2)
            int cg  = t % 16;
            #pragma unroll
            for (int r=0;r<2;r++) {
                int kk = row + r*16;
                const float4 x4 = *(const float4*)(&x[((size_t)b*CC + k0+kk)*NN + n0 + cg*4]);
                *(float4*)(&Bs[kk][cg*4]) = x4;
            }
        }
        __syncthreads();
        #pragma unroll 8
        for (int kk=0; kk<32; ++kk) {
            float a[4], bv[4];
            #pragma unroll
            for (int i=0;i<4;i++) a[i] = As[kk][tm*4+i];
            #pragma unroll
            for (int j=0;j<4;j++) bv[j] = Bs[kk][tn*4+j];
            #pragma unroll
            for (int i=0;i<4;i++)
                #pragma unroll
                for (int j=0;j<4;j++)
                    acc[i][j] = fmaf(a[i], bv[j], acc[i][j]);
        }
        __syncthreads();
    }
    const int part = o0 / CC;             // 0=q 1=k 2=v (fixed per block)
    const int h    = (o0 % CC) / DDIM;    // fixed per block
    float* dst = (part==0)? q : (part==1)? k : v;
    #pragma unroll
    for (int i=0;i<4;i++) {
        int d = tm*4+i;
        float bv = bias[o0 + d];
        float4 o4;
        o4.x = acc[i][0]+bv; o4.y = acc[i][1]+bv; o4.z = acc[i][2]+bv; o4.w = acc[i][3]+bv;
        *(float4*)(&dst[ (((size_t)b*NH + h)*DDIM + d)*NN + n0 + tn*4 ]) = o4;
    }
}

// ---------------- Flash attention (fp32) ----------------
// 1 block = (b, h, 64-query tile); loops 64-key tiles with online softmax.
__global__ __launch_bounds__(256)
void attn_kernel(const float* __restrict__ q, const float* __restrict__ k,
                 const float* __restrict__ v, const float* __restrict__ mask,
                 float* __restrict__ ao) {
    const int qt = blockIdx.x;  // 0..63
    const int h  = blockIdx.y;
    const int b  = blockIdx.z;
    const int t  = threadIdx.x;
    const int n0 = qt*64;
    const size_t bh = (size_t)b*NH + h;
    const float* qp = q + bh*DDIM*NN;
    const float* kp = k + bh*DDIM*NN;
    const float* vp = v + bh*DDIM*NN;

    __shared__ float Qs[64][65];
    __shared__ float Ks[64][65];
    __shared__ float Vs[64][65];
    __shared__ float Ss[64][65];
    __shared__ float mb[64];
    __shared__ float alphas[64];
    __shared__ float rowl[64];
    __shared__ float rowm[64];

    {   // load Q tile -> Qs[qn][d]
        int qn = t % 64;
        int d0 = t / 64;
        #pragma unroll
        for (int r=0;r<16;r++) {
            int d = d0*16 + r;
            Qs[qn][d] = qp[(size_t)d*NN + n0 + qn];
        }
    }
    if (t < 64) { rowm[t] = -1e30f; rowl[t] = 0.f; }

    const int tm = t/16, tn = t%16;
    float acc[4][4];
    #pragma unroll
    for (int i=0;i<4;i++)
        #pragma unroll
        for (int j=0;j<4;j++) acc[i][j]=0.f;

    for (int kt=0; kt<64; ++kt) {
        const int kbase = kt*64;
        {   // K,V tiles -> [kn][d]
            int kn = t % 64;
            int d0 = t / 64;
            #pragma unroll
            for (int r=0;r<16;r++) {
                int d = d0*16+r;
                Ks[kn][d] = kp[(size_t)d*NN + kbase + kn];
                Vs[kn][d] = vp[(size_t)d*NN + kbase + kn];
            }
        }
        if (t < 64) {
            float roi = mask[(size_t)b*NN + kbase + t];
            mb[t] = (1.f - roi) * (-10000.f);
        }
        __syncthreads();

        // S = scale * Q K^T + mask bias
        float s[4][4];
        #pragma unroll
        for (int i=0;i<4;i++)
            #pragma unroll
            for (int j=0;j<4;j++) s[i][j]=0.f;
        #pragma unroll 8
        for (int d=0; d<64; ++d) {
            float a[4], bv[4];
            #pragma unroll
            for (int i=0;i<4;i++) a[i] = Qs[tm*4+i][d];
            #pragma unroll
            for (int j=0;j<4;j++) bv[j] = Ks[tn*4+j][d];
            #pragma unroll
            for (int i=0;i<4;i++)
                #pragma unroll
                for (int j=0;j<4;j++)
                    s[i][j] = fmaf(a[i], bv[j], s[i][j]);
        }
        #pragma unroll
        for (int i=0;i<4;i++)
            #pragma unroll
            for (int j=0;j<4;j++)
                Ss[tm*4+i][tn*4+j] = s[i][j]*SCALE + mb[tn*4+j];
        __syncthreads();

        // online softmax, one row per thread (t < 64)
        if (t < 64) {
            float m_old = rowm[t];
            float tmax = -1e30f;
            #pragma unroll 8
            for (int j=0;j<64;++j) tmax = fmaxf(tmax, Ss[t][j]);
            float m_new = fmaxf(m_old, tmax);
            float alpha = __expf(m_old - m_new);
            float tsum = 0.f;
            #pragma unroll 8
            for (int j=0;j<64;++j) {
                float p = __expf(Ss[t][j] - m_new);
                Ss[t][j] = p;
                tsum += p;
            }
            rowm[t] = m_new;
            rowl[t] = rowl[t]*alpha + tsum;
            alphas[t] = alpha;
        }
        __syncthreads();

        // acc = acc*alpha + P @ V
        float pv[4][4];
        #pragma unroll
        for (int i=0;i<4;i++)
            #pragma unroll
            for (int j=0;j<4;j++) pv[i][j]=0.f;
        #pragma unroll 8
        for (int kn=0; kn<64; ++kn) {
            float p[4], vv[4];
            #pragma unroll
            for (int i=0;i<4;i++) p[i] = Ss[tm*4+i][kn];
            #pragma unroll
            for (int j=0;j<4;j++) vv[j] = Vs[kn][tn*4+j];
            #pragma unroll
            for (int i=0;i<4;i++)
                #pragma unroll
                for (int j=0;j<4;j++)
                    pv[i][j] = fmaf(p[i], vv[j], pv[i][j]);
        }
        #pragma unroll
        for (int i=0;i<4;i++) {
            float al = alphas[tm*4+i];
            #pragma unroll
            for (int j=0;j<4;j++)
                acc[i][j] = acc[i][j]*al + pv[i][j];
        }
        __syncthreads();
    }
    // normalize + write ao[b][n][c], c = h*64 + d
    #pragma unroll
    for (int i=0;i<4;i++) {
        int qn = tm*4+i;
        float inv = 1.f / rowl[qn];
        float4 o4;
        o4.x = acc[i][0]*inv; o4.y = acc[i][1]*inv; o4.z = acc[i][2]*inv; o4.w = acc[i][3]*inv;
        *(float4*)(&ao[ ((size_t)b*NN + n0+qn)*CC + h*DDIM + tn*4 ]) = o4;
    }
}

// ---------------- Proj GEMM ----------------
// out[b][o][n] = sum_c Wproj[o][c] * ao[b][n][c] + bproj[o]
__global__ __launch_bounds__(256)
void proj_kernel(const float* __restrict__ A, const float* __restrict__ W,
                 const float* __restrict__ bias, float* __restrict__ out) {
    const int nt = blockIdx.x;   // 64
    const int ot = blockIdx.y;   // 8
    const int b  = blockIdx.z;
    const int t  = threadIdx.x;
    const int o0 = ot*64, n0 = nt*64;
    __shared__ float As[32][65];
    __shared__ float Bs[32][65];
    const int tm=t/16, tn=t%16;
    float acc[4][4];
    #pragma unroll
    for (int i=0;i<4;i++)
        #pragma unroll
        for (int j=0;j<4;j++) acc[i][j]=0.f;

    for (int k0=0;k0<CC;k0+=32) {
        {   // W tile
            int row=t/8, cg=t%8;
            #pragma unroll
            for (int r=0;r<2;r++){
                int m=row+r*32;
                float4 w4 = *(const float4*)(&W[(size_t)(o0+m)*CC + k0+cg*4]);
                As[cg*4+0][m]=w4.x; As[cg*4+1][m]=w4.y; As[cg*4+2][m]=w4.z; As[cg*4+3][m]=w4.w;
            }
        }
        {   // A tile: A[b][n0+j][c0+k], contiguous in c -> transpose into Bs[k][j]
            int row=t/8, cg=t%8;
            #pragma unroll
            for (int r=0;r<2;r++){
                int j=row+r*32;
                float4 a4 = *(const float4*)(&A[ ((size_t)b*NN + n0+j)*CC + k0+cg*4 ]);
                Bs[cg*4+0][j]=a4.x; Bs[cg*4+1][j]=a4.y; Bs[cg*4+2][j]=a4.z; Bs[cg*4+3][j]=a4.w;
            }
        }
        __syncthreads();
        #pragma unroll 8
        for (int kk=0;kk<32;++kk){
            float a[4],bv[4];
            #pragma unroll
            for (int i=0;i<4;i++) a[i]=As[kk][tm*4+i];
            #pragma unroll
            for (int j=0;j<4;j++) bv[j]=Bs[kk][tn*4+j];
            #pragma unroll
            for (int i=0;i<4;i++)
                #pragma unroll
                for (int j=0;j<4;j++)
                    acc[i][j]=fmaf(a[i],bv[j],acc[i][j]);
        }
        __syncthreads();
    }
    #pragma unroll
    for (int i=0;i<4;i++){
        float bv = bias[o0+tm*4+i];
        float4 o4;
        o4.x=acc[i][0]+bv; o4.y=acc[i][1]+bv; o4.z=acc[i][2]+bv; o4.w=acc[i][3]+bv;
        *(float4*)(&out[ ((size_t)b*CC + o0+tm*4+i)*NN + n0 + tn*4 ]) = o4;
    }
}

extern "C" void kernel_launch(void* const* d_in, const int* in_sizes, int n_in,
                              void* d_out, int out_size, void* d_ws, size_t ws_size,
                              hipStream_t stream) {
    const float* x     = (const float*)d_in[0];
    const float* mask  = (const float*)d_in[1];
    const float* Wqkv  = (const float*)d_in[2];
    const float* bqkv  = (const float*)d_in[3];
    const float* Wproj = (const float*)d_in[4];
    const float* bproj = (const float*)d_in[5];
    float* out = (float*)d_out;

    const size_t per = (size_t)BB*NH*DDIM*NN;   // 4,194,304 floats (16 MB)
    float* q  = (float*)d_ws;
    float* k  = q + per;
    float* v  = k + per;
    float* ao = v + per;                        // [B][N][C]

    qkv_kernel<<<dim3(64,24,BB), 256, 0, stream>>>(x, Wqkv, bqkv, q, k, v);
    attn_kernel<<<dim3(64,NH,BB), 256, 0, stream>>>(q, k, v, mask, ao);
    proj_kernel<<<dim3(64,NH,BB), 256, 0, stream>>>(ao, Wproj, bproj, out);
}

// Round 2
// 552.478 us; speedup vs baseline: 4.0162x; 4.0162x over previous
//
#include <hip/hip_runtime.h>

#define BB 2
#define CC 512
#define NH 8
#define DDIM 64
#define NN 4096
#define SCALE 0.125f

typedef __bf16 bfx8 __attribute__((ext_vector_type(8)));
typedef float  f32x4 __attribute__((ext_vector_type(4)));

__device__ inline ushort f2bf(float f) {
  union { float f; unsigned u; } x; x.f = f;
  unsigned r = x.u + 0x7fffu + ((x.u >> 16) & 1u);
  return (ushort)(r >> 16);
}

// ---------------- QKV GEMM (fp32 compute, bf16 output) ----------------
// q,k stored [B][NH][N][D]; v stored [B][NH][D][N].
__global__ __launch_bounds__(256)
void qkv_kernel(const float* __restrict__ x, const float* __restrict__ W,
                const float* __restrict__ bias, ushort* __restrict__ qws,
                ushort* __restrict__ kws, ushort* __restrict__ vws) {
    const int nt = blockIdx.x;      // 64 n-tiles
    const int ot = blockIdx.y;      // 24 o-tiles
    const int b  = blockIdx.z;
    const int t  = threadIdx.x;
    const int o0 = ot * 64;
    const int n0 = nt * 64;

    __shared__ float As[32][65];
    __shared__ float Bs[32][68];

    const int tm = t / 16;
    const int tn = t % 16;

    float acc[4][4];
    #pragma unroll
    for (int i=0;i<4;i++)
        #pragma unroll
        for (int j=0;j<4;j++) acc[i][j]=0.f;

    for (int k0 = 0; k0 < CC; k0 += 32) {
        {   // W tile 64(o) x 32(c)
            int row = t / 8, cg = t % 8;
            #pragma unroll
            for (int r=0;r<2;r++) {
                int m = row + r*32;
                const float4 w4 = *(const float4*)(&W[(size_t)(o0+m)*CC + k0 + cg*4]);
                As[cg*4+0][m] = w4.x; As[cg*4+1][m] = w4.y;
                As[cg*4+2][m] = w4.z; As[cg*4+3][m] = w4.w;
            }
        }
        {   // x tile 32(c) x 64(n)
            int row = t / 16, cg = t % 16;
            #pragma unroll
            for (int r=0;r<2;r++) {
                int kk = row + r*16;
                const float4 x4 = *(const float4*)(&x[((size_t)b*CC + k0+kk)*NN + n0 + cg*4]);
                *(float4*)(&Bs[kk][cg*4]) = x4;
            }
        }
        __syncthreads();
        #pragma unroll 8
        for (int kk=0; kk<32; ++kk) {
            float a[4], bv[4];
            #pragma unroll
            for (int i=0;i<4;i++) a[i] = As[kk][tm*4+i];
            #pragma unroll
            for (int j=0;j<4;j++) bv[j] = Bs[kk][tn*4+j];
            #pragma unroll
            for (int i=0;i<4;i++)
                #pragma unroll
                for (int j=0;j<4;j++)
                    acc[i][j] = fmaf(a[i], bv[j], acc[i][j]);
        }
        __syncthreads();
    }
    const int part = o0 / CC;             // 0=q 1=k 2=v
    const int h    = (o0 % CC) / DDIM;
    float bb[4];
    #pragma unroll
    for (int i=0;i<4;i++) bb[i] = bias[o0 + tm*4 + i];

    if (part < 2) {
        ushort* dst = (part==0 ? qws : kws) + ((size_t)b*NH + h)*(size_t)NN*DDIM;
        #pragma unroll
        for (int j=0;j<4;j++) {
            int n = n0 + tn*4 + j;
            ushort4 pk;
            pk.x = f2bf(acc[0][j] + bb[0]);
            pk.y = f2bf(acc[1][j] + bb[1]);
            pk.z = f2bf(acc[2][j] + bb[2]);
            pk.w = f2bf(acc[3][j] + bb[3]);
            *(ushort4*)(&dst[(size_t)n*DDIM + tm*4]) = pk;
        }
    } else {
        ushort* dst = vws + ((size_t)b*NH + h)*(size_t)DDIM*NN;
        #pragma unroll
        for (int i=0;i<4;i++) {
            int d = tm*4 + i;
            ushort4 pk;
            pk.x = f2bf(acc[i][0] + bb[i]);
            pk.y = f2bf(acc[i][1] + bb[i]);
            pk.z = f2bf(acc[i][2] + bb[i]);
            pk.w = f2bf(acc[i][3] + bb[i]);
            *(ushort4*)(&dst[(size_t)d*NN + n0 + tn*4]) = pk;
        }
    }
}

// ---------------- Flash attention (bf16 MFMA) ----------------
// Block: 256 thr = 4 waves; wave w owns q rows [n0+w*16, +16). 64-key tiles.
__global__ __launch_bounds__(256)
void attn_mfma(const ushort* __restrict__ qw, const ushort* __restrict__ kw,
               const ushort* __restrict__ vw, const float* __restrict__ mask,
               float* __restrict__ ao) {
    const int qt = blockIdx.x, h = blockIdx.y, b = blockIdx.z;
    const int t = threadIdx.x;
    const int w = t >> 6, l = t & 63, g = l >> 4, m = l & 15;
    const int n0 = qt * 64;
    const size_t bh = (size_t)b * NH + h;
    const ushort* qp = qw + bh * (size_t)NN * DDIM;
    const ushort* kp = kw + bh * (size_t)NN * DDIM;
    const ushort* vp = vw + bh * (size_t)DDIM * NN;

    __shared__ __align__(16) ushort Ks[64*64];      // [key][d], chunk-swizzled
    __shared__ __align__(16) ushort Vs[64*64];      // [d][key], chunk-swizzled
    __shared__ __align__(16) ushort Ps[4][16*64];   // per-wave [qrow][key], swizzled
    __shared__ float mb[64];

    // Q fragments hoisted to registers (A-frag: row=m, k=kc*32+g*8+i)
    bfx8 qf[2];
    #pragma unroll
    for (int kc = 0; kc < 2; ++kc)
        qf[kc] = *(const bfx8*)(qp + (size_t)(n0 + w*16 + m)*DDIM + kc*32 + g*8);

    f32x4 o[4];
    #pragma unroll
    for (int f=0; f<4; ++f) o[f] = (f32x4){0.f,0.f,0.f,0.f};
    float m_run[4], l_run[4];
    #pragma unroll
    for (int r=0; r<4; ++r) { m_run[r] = -1e30f; l_run[r] = 0.f; }

    // prefetch tile 0 into regs
    float4 kreg0, kreg1, vreg0, vreg1;
    float mreg = 0.f;
    kreg0 = *(const float4*)(kp + (size_t)t*8);
    kreg1 = *(const float4*)(kp + (size_t)(t+256)*8);
    vreg0 = *(const float4*)(vp + (size_t)(t>>3)*NN + (t&7)*8);
    vreg1 = *(const float4*)(vp + (size_t)((t+256)>>3)*NN + ((t+256)&7)*8);
    if (t < 64) mreg = mask[(size_t)b*NN + t];

    for (int kt = 0; kt < 64; ++kt) {
        __syncthreads();   // previous tile's LDS reads complete
        {   // stage regs -> LDS (chunk-swizzled: chunk ^= row&7)
            int row = t >> 3, c = t & 7;
            *(float4*)(&Ks[row*64 + ((c ^ (row&7))*8)]) = kreg0;
            *(float4*)(&Vs[row*64 + ((c ^ (row&7))*8)]) = vreg0;
            int t1 = t + 256, row1 = t1 >> 3, c1 = t1 & 7;
            *(float4*)(&Ks[row1*64 + ((c1 ^ (row1&7))*8)]) = kreg1;
            *(float4*)(&Vs[row1*64 + ((c1 ^ (row1&7))*8)]) = vreg1;
            if (t < 64) mb[t] = (1.f - mreg) * (-10000.f);
        }
        __syncthreads();
        if (kt + 1 < 64) {  // prefetch next tile (in flight under compute)
            const int nb = (kt + 1) * 64;
            kreg0 = *(const float4*)(kp + (size_t)nb*DDIM + t*8);
            kreg1 = *(const float4*)(kp + (size_t)nb*DDIM + (t+256)*8);
            vreg0 = *(const float4*)(vp + (size_t)(t>>3)*NN + nb + (t&7)*8);
            vreg1 = *(const float4*)(vp + (size_t)((t+256)>>3)*NN + nb + ((t+256)&7)*8);
            if (t < 64) mreg = mask[(size_t)b*NN + nb + t];
        }

        // ---- S = Q K^T (strip 16q x 64keys per wave) ----
        f32x4 sa[4];
        #pragma unroll
        for (int f=0; f<4; ++f) sa[f] = (f32x4){0.f,0.f,0.f,0.f};
        #pragma unroll
        for (int kc=0; kc<2; ++kc) {
            #pragma unroll
            for (int f=0; f<4; ++f) {
                int row = f*16 + m;
                bfx8 kf = *(const bfx8*)(&Ks[row*64 + ((kc*32 + g*8) ^ ((row&7)*8))]);
                sa[f] = __builtin_amdgcn_mfma_f32_16x16x32_bf16(qf[kc], kf, sa[f], 0, 0, 0);
            }
        }

        // ---- bias + online softmax (rows g*4+r, cols f*16+m) ----
        float p[4][4];
        float tmax[4] = {-1e30f,-1e30f,-1e30f,-1e30f};
        #pragma unroll
        for (int f=0; f<4; ++f) {
            float mbv = mb[f*16 + m];
            #pragma unroll
            for (int r=0; r<4; ++r) {
                float sv = sa[f][r] * SCALE + mbv;
                p[f][r] = sv;
                tmax[r] = fmaxf(tmax[r], sv);
            }
        }
        #pragma unroll
        for (int mk=1; mk<=8; mk<<=1)
            #pragma unroll
            for (int r=0; r<4; ++r)
                tmax[r] = fmaxf(tmax[r], __shfl_xor(tmax[r], mk));
        float alpha[4], rsum[4];
        #pragma unroll
        for (int r=0; r<4; ++r) {
            float mn = fmaxf(m_run[r], tmax[r]);
            alpha[r] = __expf(m_run[r] - mn);
            m_run[r] = mn;
            rsum[r] = 0.f;
        }
        #pragma unroll
        for (int f=0; f<4; ++f)
            #pragma unroll
            for (int r=0; r<4; ++r) {
                p[f][r] = __expf(p[f][r] - m_run[r]);
                rsum[r] += p[f][r];
            }
        #pragma unroll
        for (int mk=1; mk<=8; mk<<=1)
            #pragma unroll
            for (int r=0; r<4; ++r)
                rsum[r] += __shfl_xor(rsum[r], mk);
        #pragma unroll
        for (int r=0; r<4; ++r)
            l_run[r] = l_run[r]*alpha[r] + rsum[r];

        // ---- write P (bf16, swizzled) + rescale O ----
        #pragma unroll
        for (int f=0; f<4; ++f) {
            #pragma unroll
            for (int r=0; r<4; ++r) {
                int row = g*4 + r, col = f*16 + m;
                Ps[w][row*64 + (col ^ ((row&7)*8))] = f2bf(p[f][r]);
                o[f][r] *= alpha[r];
            }
        }

        // ---- O += P V ----
        #pragma unroll
        for (int kc=0; kc<2; ++kc) {
            bfx8 pf = *(const bfx8*)(&Ps[w][m*64 + ((kc*32 + g*8) ^ ((m&7)*8))]);
            #pragma unroll
            for (int f=0; f<4; ++f) {
                int row = f*16 + m;
                bfx8 vf = *(const bfx8*)(&Vs[row*64 + ((kc*32 + g*8) ^ ((row&7)*8))]);
                o[f] = __builtin_amdgcn_mfma_f32_16x16x32_bf16(pf, vf, o[f], 0, 0, 0);
            }
        }
    }

    // ---- normalize + write ao[b][n][c] (fp32) ----
    #pragma unroll
    for (int r=0; r<4; ++r) l_run[r] = 1.f / l_run[r];
    #pragma unroll
    for (int f=0; f<4; ++f)
        #pragma unroll
        for (int r=0; r<4; ++r)
            ao[((size_t)b*NN + n0 + w*16 + g*4 + r)*CC + h*DDIM + f*16 + m] = o[f][r] * l_run[r];
}

// ---------------- Proj GEMM (fp32) ----------------
__global__ __launch_bounds__(256)
void proj_kernel(const float* __restrict__ A, const float* __restrict__ W,
                 const float* __restrict__ bias, float* __restrict__ out) {
    const int nt = blockIdx.x;
    const int ot = blockIdx.y;
    const int b  = blockIdx.z;
    const int t  = threadIdx.x;
    const int o0 = ot*64, n0 = nt*64;
    __shared__ float As[32][65];
    __shared__ float Bs[32][65];
    const int tm=t/16, tn=t%16;
    float acc[4][4];
    #pragma unroll
    for (int i=0;i<4;i++)
        #pragma unroll
        for (int j=0;j<4;j++) acc[i][j]=0.f;

    for (int k0=0;k0<CC;k0+=32) {
        {
            int row=t/8, cg=t%8;
            #pragma unroll
            for (int r=0;r<2;r++){
                int mrow=row+r*32;
                float4 w4 = *(const float4*)(&W[(size_t)(o0+mrow)*CC + k0+cg*4]);
                As[cg*4+0][mrow]=w4.x; As[cg*4+1][mrow]=w4.y;
                As[cg*4+2][mrow]=w4.z; As[cg*4+3][mrow]=w4.w;
            }
        }
        {
            int row=t/8, cg=t%8;
            #pragma unroll
            for (int r=0;r<2;r++){
                int j=row+r*32;
                float4 a4 = *(const float4*)(&A[ ((size_t)b*NN + n0+j)*CC + k0+cg*4 ]);
                Bs[cg*4+0][j]=a4.x; Bs[cg*4+1][j]=a4.y;
                Bs[cg*4+2][j]=a4.z; Bs[cg*4+3][j]=a4.w;
            }
        }
        __syncthreads();
        #pragma unroll 8
        for (int kk=0;kk<32;++kk){
            float a[4],bv[4];
            #pragma unroll
            for (int i=0;i<4;i++) a[i]=As[kk][tm*4+i];
            #pragma unroll
            for (int j=0;j<4;j++) bv[j]=Bs[kk][tn*4+j];
            #pragma unroll
            for (int i=0;i<4;i++)
                #pragma unroll
                for (int j=0;j<4;j++)
                    acc[i][j]=fmaf(a[i],bv[j],acc[i][j]);
        }
        __syncthreads();
    }
    #pragma unroll
    for (int i=0;i<4;i++){
        float bv = bias[o0+tm*4+i];
        float4 o4;
        o4.x=acc[i][0]+bv; o4.y=acc[i][1]+bv; o4.z=acc[i][2]+bv; o4.w=acc[i][3]+bv;
        *(float4*)(&out[ ((size_t)b*CC + o0+tm*4+i)*NN + n0 + tn*4 ]) = o4;
    }
}

extern "C" void kernel_launch(void* const* d_in, const int* in_sizes, int n_in,
                              void* d_out, int out_size, void* d_ws, size_t ws_size,
                              hipStream_t stream) {
    const float* x     = (const float*)d_in[0];
    const float* mask  = (const float*)d_in[1];
    const float* Wqkv  = (const float*)d_in[2];
    const float* bqkv  = (const float*)d_in[3];
    const float* Wproj = (const float*)d_in[4];
    const float* bproj = (const float*)d_in[5];
    float* out = (float*)d_out;

    const size_t per = (size_t)BB*NH*NN*DDIM;   // 4,194,304 elems
    ushort* qws = (ushort*)d_ws;
    ushort* kws = qws + per;
    ushort* vws = kws + per;
    float*  ao  = (float*)(vws + per);          // [B][N][C] fp32

    qkv_kernel<<<dim3(64,24,BB), 256, 0, stream>>>(x, Wqkv, bqkv, qws, kws, vws);
    attn_mfma<<<dim3(64,NH,BB), 256, 0, stream>>>(qws, kws, vws, mask, ao);
    proj_kernel<<<dim3(64,NH,BB), 256, 0, stream>>>(ao, Wproj, bproj, out);
}

// Round 3
// 339.831 us; speedup vs baseline: 6.5293x; 1.6257x over previous
//
#include <hip/hip_runtime.h>

#define BB 2
#define CC 512
#define NH 8
#define DDIM 64
#define NN 4096
#define SCALE 0.125f

typedef __bf16 bfx8 __attribute__((ext_vector_type(8)));
typedef float  f32x4 __attribute__((ext_vector_type(4)));

__device__ inline ushort f2bf(float f) {
  union { float f; unsigned u; } x; x.f = f;
  unsigned r = x.u + 0x7fffu + ((x.u >> 16) & 1u);
  return (ushort)(r >> 16);
}

__device__ __forceinline__ void gload_lds16(const void* g, void* l) {
  __builtin_amdgcn_global_load_lds(
      (const __attribute__((address_space(1))) void*)g,
      (__attribute__((address_space(3))) void*)l, 16, 0, 0);
}

// ---------------- weight convert fp32 -> bf16 ----------------
__global__ __launch_bounds__(256)
void convert_w(const float* __restrict__ Wqkv, const float* __restrict__ Wproj,
               ushort* __restrict__ Wq, ushort* __restrict__ Wp) {
    const int n1 = (1536*CC)/4;
    const int n2 = (CC*CC)/4;
    int i = blockIdx.x*256 + threadIdx.x;
    if (i < n1) {
        float4 v = *(const float4*)(&Wqkv[(size_t)i*4]);
        ushort4 o; o.x=f2bf(v.x); o.y=f2bf(v.y); o.z=f2bf(v.z); o.w=f2bf(v.w);
        *(ushort4*)(&Wq[(size_t)i*4]) = o;
    } else if (i < n1+n2) {
        int j = i - n1;
        float4 v = *(const float4*)(&Wproj[(size_t)j*4]);
        ushort4 o; o.x=f2bf(v.x); o.y=f2bf(v.y); o.z=f2bf(v.z); o.w=f2bf(v.w);
        *(ushort4*)(&Wp[(size_t)j*4]) = o;
    }
}

// ---------------- transpose x [B][C][N] f32 -> xT [B][N][C] bf16 ----------------
__global__ __launch_bounds__(256)
void transpose_x(const float* __restrict__ x, ushort* __restrict__ xT) {
    const int bn = blockIdx.x, bc = blockIdx.y, b = blockIdx.z;
    const int t = threadIdx.x;
    __shared__ float T[64][65];
    const int n0 = bn*64, c0 = bc*64;
    const int tc = t >> 4, tn4 = (t & 15) * 4;
    #pragma unroll
    for (int r = 0; r < 4; ++r) {
        int c = tc + r*16;
        float4 v = *(const float4*)(&x[((size_t)b*CC + c0 + c)*NN + n0 + tn4]);
        T[c][tn4+0] = v.x; T[c][tn4+1] = v.y; T[c][tn4+2] = v.z; T[c][tn4+3] = v.w;
    }
    __syncthreads();
    #pragma unroll
    for (int r = 0; r < 4; ++r) {
        int n = tc + r*16;
        ushort4 o;
        o.x = f2bf(T[tn4+0][n]); o.y = f2bf(T[tn4+1][n]);
        o.z = f2bf(T[tn4+2][n]); o.w = f2bf(T[tn4+3][n]);
        *(ushort4*)(&xT[((size_t)b*NN + n0 + n)*CC + c0 + tn4]) = o;
    }
}

// ---------------- QKV GEMM (bf16 MFMA) ----------------
// xT [B][N][C], Wb [1536][C]. q,k -> [B][NH][N][D]; v -> [B][NH][D][N].
__global__ __launch_bounds__(256)
void qkv_mfma(const ushort* __restrict__ xT, const ushort* __restrict__ Wb,
              const float* __restrict__ bias, ushort* __restrict__ qws,
              ushort* __restrict__ kws, ushort* __restrict__ vws) {
    const int bn = blockIdx.x;   // 32 n-tiles
    const int bo = blockIdx.y;   // 12 o-tiles
    const int b  = blockIdx.z;
    const int t  = threadIdx.x;
    const int w  = t >> 6, l = t & 63, g = l >> 4, m = l & 15;
    const int o0 = bo * 128, n0 = bn * 128;
    const int part = o0 >> 9;    // 0=q 1=k 2=v
    const int wr = w >> 1, wc = w & 1;

    __shared__ __align__(16) ushort Xs[128*64];
    __shared__ __align__(16) ushort Ws_[128*64];

    const ushort* xbase = xT + ((size_t)b*NN + n0)*CC;
    const ushort* wbase = Wb + (size_t)o0*CC;

    f32x4 acc[4][4];
    #pragma unroll
    for (int i=0;i<4;i++)
        #pragma unroll
        for (int j=0;j<4;j++) acc[i][j] = (f32x4){0.f,0.f,0.f,0.f};

    const ushort* R = (part < 2) ? Xs  : Ws_;   // rows side (MFMA A)
    const ushort* Cc = (part < 2) ? Ws_ : Xs;   // cols side (MFMA B)

    for (int k0 = 0; k0 < CC; k0 += 64) {
        #pragma unroll
        for (int it = 0; it < 4; ++it) {
            int c16 = (it*4 + w)*64 + l;
            int row = c16 >> 3;
            int gch = (c16 & 7) ^ (row & 7);    // inverse-swizzled source
            gload_lds16(xbase + (size_t)row*CC + k0 + gch*8, Xs  + c16*8);
            gload_lds16(wbase + (size_t)row*CC + k0 + gch*8, Ws_ + c16*8);
        }
        __syncthreads();
        __builtin_amdgcn_s_setprio(1);
        #pragma unroll
        for (int kc = 0; kc < 2; ++kc) {
            bfx8 ra[4], cb[4];
            #pragma unroll
            for (int f = 0; f < 4; ++f) {
                int rrow = wr*64 + f*16 + m;
                ra[f] = *(const bfx8*)(R  + (rrow*8 + ((kc*4+g) ^ (rrow&7)))*8);
                int crow = wc*64 + f*16 + m;
                cb[f] = *(const bfx8*)(Cc + (crow*8 + ((kc*4+g) ^ (crow&7)))*8);
            }
            #pragma unroll
            for (int i = 0; i < 4; ++i)
                #pragma unroll
                for (int j = 0; j < 4; ++j)
                    acc[i][j] = __builtin_amdgcn_mfma_f32_16x16x32_bf16(ra[i], cb[j], acc[i][j], 0, 0, 0);
        }
        __builtin_amdgcn_s_setprio(0);
        __syncthreads();
    }

    if (part < 2) {
        // rows = n, cols = o. dst [bh][n][d]
        ushort* dst = (part == 0) ? qws : kws;
        #pragma unroll
        for (int j = 0; j < 4; ++j) {
            int o = o0 + wc*64 + j*16 + m;
            int ol = o & 511;
            int h = ol >> 6, d = ol & 63;
            float bv = bias[o];
            ushort* dp = dst + ((size_t)b*NH + h)*(size_t)NN*DDIM + d;
            #pragma unroll
            for (int i = 0; i < 4; ++i) {
                #pragma unroll
                for (int r = 0; r < 4; ++r) {
                    int n = n0 + wr*64 + i*16 + g*4 + r;
                    dp[(size_t)n*DDIM] = f2bf(acc[i][j][r] + bv);
                }
            }
        }
    } else {
        // rows = o, cols = n. dst v [bh][d][n]
        #pragma unroll
        for (int i = 0; i < 4; ++i) {
            #pragma unroll
            for (int r = 0; r < 4; ++r) {
                int o = o0 + wr*64 + i*16 + g*4 + r;
                int vo = o - 1024;
                int h = vo >> 6, d = vo & 63;
                float bv = bias[o];
                ushort* dp = vws + (((size_t)b*NH + h)*DDIM + d)*NN;
                #pragma unroll
                for (int j = 0; j < 4; ++j) {
                    int n = n0 + wc*64 + j*16 + m;
                    dp[n] = f2bf(acc[i][j][r] + bv);
                }
            }
        }
    }
}

// ---------------- Flash attention (bf16 MFMA) ----------------
__global__ __launch_bounds__(256)
void attn_mfma(const ushort* __restrict__ qw, const ushort* __restrict__ kw,
               const ushort* __restrict__ vw, const float* __restrict__ mask,
               ushort* __restrict__ aob) {
    const int qt = blockIdx.x, h = blockIdx.y, b = blockIdx.z;
    const int t = threadIdx.x;
    const int w = t >> 6, l = t & 63, g = l >> 4, m = l & 15;
    const int n0 = qt * 64;
    const size_t bh = (size_t)b * NH + h;
    const ushort* qp = qw + bh * (size_t)NN * DDIM;
    const ushort* kp = kw + bh * (size_t)NN * DDIM;
    const ushort* vp = vw + bh * (size_t)DDIM * NN;

    __shared__ __align__(16) ushort Ks[64*64];
    __shared__ __align__(16) ushort Vs[64*64];
    __shared__ __align__(16) ushort Ps[4][16*64];
    __shared__ float mb[64];

    bfx8 qf[2];
    #pragma unroll
    for (int kc = 0; kc < 2; ++kc)
        qf[kc] = *(const bfx8*)(qp + (size_t)(n0 + w*16 + m)*DDIM + kc*32 + g*8);

    f32x4 o[4];
    #pragma unroll
    for (int f=0; f<4; ++f) o[f] = (f32x4){0.f,0.f,0.f,0.f};
    float m_run[4], l_run[4];
    #pragma unroll
    for (int r=0; r<4; ++r) { m_run[r] = -1e30f; l_run[r] = 0.f; }

    float4 kreg0, kreg1, vreg0, vreg1;
    float mreg = 0.f;
    kreg0 = *(const float4*)(kp + (size_t)t*8);
    kreg1 = *(const float4*)(kp + (size_t)(t+256)*8);
    vreg0 = *(const float4*)(vp + (size_t)(t>>3)*NN + (t&7)*8);
    vreg1 = *(const float4*)(vp + (size_t)((t+256)>>3)*NN + ((t+256)&7)*8);
    if (t < 64) mreg = mask[(size_t)b*NN + t];

    for (int kt = 0; kt < 64; ++kt) {
        __syncthreads();
        {
            int row = t >> 3, c = t & 7;
            *(float4*)(&Ks[row*64 + ((c ^ (row&7))*8)]) = kreg0;
            *(float4*)(&Vs[row*64 + ((c ^ (row&7))*8)]) = vreg0;
            int t1 = t + 256, row1 = t1 >> 3, c1 = t1 & 7;
            *(float4*)(&Ks[row1*64 + ((c1 ^ (row1&7))*8)]) = kreg1;
            *(float4*)(&Vs[row1*64 + ((c1 ^ (row1&7))*8)]) = vreg1;
            if (t < 64) mb[t] = (1.f - mreg) * (-10000.f);
        }
        __syncthreads();
        if (kt + 1 < 64) {
            const int nb = (kt + 1) * 64;
            kreg0 = *(const float4*)(kp + (size_t)nb*DDIM + t*8);
            kreg1 = *(const float4*)(kp + (size_t)nb*DDIM + (t+256)*8);
            vreg0 = *(const float4*)(vp + (size_t)(t>>3)*NN + nb + (t&7)*8);
            vreg1 = *(const float4*)(vp + (size_t)((t+256)>>3)*NN + nb + ((t+256)&7)*8);
            if (t < 64) mreg = mask[(size_t)b*NN + nb + t];
        }

        // ---- S = Q K^T ----
        f32x4 sa[4];
        #pragma unroll
        for (int f=0; f<4; ++f) sa[f] = (f32x4){0.f,0.f,0.f,0.f};
        __builtin_amdgcn_s_setprio(1);
        #pragma unroll
        for (int kc=0; kc<2; ++kc) {
            #pragma unroll
            for (int f=0; f<4; ++f) {
                int row = f*16 + m;
                bfx8 kf = *(const bfx8*)(&Ks[row*64 + ((kc*32 + g*8) ^ ((row&7)*8))]);
                sa[f] = __builtin_amdgcn_mfma_f32_16x16x32_bf16(qf[kc], kf, sa[f], 0, 0, 0);
            }
        }
        __builtin_amdgcn_s_setprio(0);

        // ---- bias + online softmax (rows g*4+r, cols f*16+m) ----
        float p[4][4];
        float tmax[4] = {-1e30f,-1e30f,-1e30f,-1e30f};
        #pragma unroll
        for (int f=0; f<4; ++f) {
            float mbv = mb[f*16 + m];
            #pragma unroll
            for (int r=0; r<4; ++r) {
                float sv = sa[f][r] * SCALE + mbv;
                p[f][r] = sv;
                tmax[r] = fmaxf(tmax[r], sv);
            }
        }
        #pragma unroll
        for (int mk=1; mk<=8; mk<<=1)
            #pragma unroll
            for (int r=0; r<4; ++r)
                tmax[r] = fmaxf(tmax[r], __shfl_xor(tmax[r], mk));

        // T13 defer-max: only rescale when some row grew past threshold
        bool defer = true;
        #pragma unroll
        for (int r=0; r<4; ++r) defer = defer && (tmax[r] <= m_run[r] + 8.f);
        if (!__all((int)defer)) {
            #pragma unroll
            for (int r=0; r<4; ++r) {
                float mn = fmaxf(m_run[r], tmax[r]);
                float al = __expf(m_run[r] - mn);
                m_run[r] = mn;
                l_run[r] *= al;
                tmax[r] = al;   // reuse as alpha
            }
            #pragma unroll
            for (int f=0; f<4; ++f)
                #pragma unroll
                for (int r=0; r<4; ++r) o[f][r] *= tmax[r];
        }
        float rsum[4] = {0.f,0.f,0.f,0.f};
        #pragma unroll
        for (int f=0; f<4; ++f)
            #pragma unroll
            for (int r=0; r<4; ++r) {
                p[f][r] = __expf(p[f][r] - m_run[r]);
                rsum[r] += p[f][r];
            }
        #pragma unroll
        for (int mk=1; mk<=8; mk<<=1)
            #pragma unroll
            for (int r=0; r<4; ++r)
                rsum[r] += __shfl_xor(rsum[r], mk);
        #pragma unroll
        for (int r=0; r<4; ++r) l_run[r] += rsum[r];

        // ---- write P (bf16, swizzled) ----
        #pragma unroll
        for (int f=0; f<4; ++f)
            #pragma unroll
            for (int r=0; r<4; ++r) {
                int row = g*4 + r, col = f*16 + m;
                Ps[w][row*64 + (col ^ ((row&7)*8))] = f2bf(p[f][r]);
            }

        // ---- O += P V ----
        __builtin_amdgcn_s_setprio(1);
        #pragma unroll
        for (int kc=0; kc<2; ++kc) {
            bfx8 pf = *(const bfx8*)(&Ps[w][m*64 + ((kc*32 + g*8) ^ ((m&7)*8))]);
            #pragma unroll
            for (int f=0; f<4; ++f) {
                int row = f*16 + m;
                bfx8 vf = *(const bfx8*)(&Vs[row*64 + ((kc*32 + g*8) ^ ((row&7)*8))]);
                o[f] = __builtin_amdgcn_mfma_f32_16x16x32_bf16(pf, vf, o[f], 0, 0, 0);
            }
        }
        __builtin_amdgcn_s_setprio(0);
    }

    #pragma unroll
    for (int r=0; r<4; ++r) l_run[r] = 1.f / l_run[r];
    #pragma unroll
    for (int f=0; f<4; ++f)
        #pragma unroll
        for (int r=0; r<4; ++r)
            aob[((size_t)b*NN + n0 + w*16 + g*4 + r)*CC + h*DDIM + f*16 + m] = f2bf(o[f][r] * l_run[r]);
}

// ---------------- Proj GEMM (bf16 MFMA, fp32 out) ----------------
// out[b][o][n] = sum_c Wp[o][c] * ao[b][n][c] + bias[o]
__global__ __launch_bounds__(256)
void proj_mfma(const ushort* __restrict__ aob, const ushort* __restrict__ Wp,
               const float* __restrict__ bias, float* __restrict__ out) {
    const int bn = blockIdx.x;   // 32
    const int bo = blockIdx.y;   // 4
    const int b  = blockIdx.z;
    const int t  = threadIdx.x;
    const int w  = t >> 6, l = t & 63, g = l >> 4, m = l & 15;
    const int o0 = bo * 128, n0 = bn * 128;
    const int wr = w >> 1, wc = w & 1;

    __shared__ __align__(16) ushort As_[128*64];  // ao rows (n)
    __shared__ __align__(16) ushort Ws_[128*64];  // W rows (o)

    const ushort* abase = aob + ((size_t)b*NN + n0)*CC;
    const ushort* wbase = Wp + (size_t)o0*CC;

    f32x4 acc[4][4];
    #pragma unroll
    for (int i=0;i<4;i++)
        #pragma unroll
        for (int j=0;j<4;j++) acc[i][j] = (f32x4){0.f,0.f,0.f,0.f};

    for (int k0 = 0; k0 < CC; k0 += 64) {
        #pragma unroll
        for (int it = 0; it < 4; ++it) {
            int c16 = (it*4 + w)*64 + l;
            int row = c16 >> 3;
            int gch = (c16 & 7) ^ (row & 7);
            gload_lds16(abase + (size_t)row*CC + k0 + gch*8, As_ + c16*8);
            gload_lds16(wbase + (size_t)row*CC + k0 + gch*8, Ws_ + c16*8);
        }
        __syncthreads();
        __builtin_amdgcn_s_setprio(1);
        #pragma unroll
        for (int kc = 0; kc < 2; ++kc) {
            bfx8 ra[4], cb[4];
            #pragma unroll
            for (int f = 0; f < 4; ++f) {
                int rrow = wr*64 + f*16 + m;    // rows = o (from W)
                ra[f] = *(const bfx8*)(Ws_ + (rrow*8 + ((kc*4+g) ^ (rrow&7)))*8);
                int crow = wc*64 + f*16 + m;    // cols = n (from ao)
                cb[f] = *(const bfx8*)(As_ + (crow*8 + ((kc*4+g) ^ (crow&7)))*8);
            }
            #pragma unroll
            for (int i = 0; i < 4; ++i)
                #pragma unroll
                for (int j = 0; j < 4; ++j)
                    acc[i][j] = __builtin_amdgcn_mfma_f32_16x16x32_bf16(ra[i], cb[j], acc[i][j], 0, 0, 0);
        }
        __builtin_amdgcn_s_setprio(0);
        __syncthreads();
    }
    #pragma unroll
    for (int i = 0; i < 4; ++i) {
        #pragma unroll
        for (int r = 0; r < 4; ++r) {
            int o = o0 + wr*64 + i*16 + g*4 + r;
            float bv = bias[o];
            float* dp = out + ((size_t)b*CC + o)*NN;
            #pragma unroll
            for (int j = 0; j < 4; ++j) {
                int n = n0 + wc*64 + j*16 + m;
                dp[n] = acc[i][j][r] + bv;
            }
        }
    }
}

extern "C" void kernel_launch(void* const* d_in, const int* in_sizes, int n_in,
                              void* d_out, int out_size, void* d_ws, size_t ws_size,
                              hipStream_t stream) {
    const float* x     = (const float*)d_in[0];
    const float* mask  = (const float*)d_in[1];
    const float* Wqkv  = (const float*)d_in[2];
    const float* bqkv  = (const float*)d_in[3];
    const float* Wproj = (const float*)d_in[4];
    const float* bproj = (const float*)d_in[5];
    float* out = (float*)d_out;

    const size_t per = (size_t)BB*NH*NN*DDIM;   // 4,194,304 elems
    ushort* qws = (ushort*)d_ws;
    ushort* kws = qws + per;
    ushort* vws = kws + per;
    ushort* xTb = vws + per;                    // [B][N][C] bf16
    ushort* aob = xTb + per;                    // [B][N][C] bf16
    ushort* Wqb = aob + per;                    // [1536][512]
    ushort* Wpb = Wqb + (size_t)1536*CC;        // [512][512]

    convert_w<<<dim3(1024), 256, 0, stream>>>(Wqkv, Wproj, Wqb, Wpb);
    transpose_x<<<dim3(64, 8, BB), 256, 0, stream>>>(x, xTb);
    qkv_mfma<<<dim3(32, 12, BB), 256, 0, stream>>>(xTb, Wqb, bqkv, qws, kws, vws);
    attn_mfma<<<dim3(64, NH, BB), 256, 0, stream>>>(qws, kws, vws, mask, aob);
    proj_mfma<<<dim3(32, 4, BB), 256, 0, stream>>>(aob, Wpb, bproj, out);
}

// Round 4
// 224.314 us; speedup vs baseline: 9.8917x; 1.5150x over previous
//
#include <hip/hip_runtime.h>

#define BB 2
#define CC 512
#define NH 8
#define DDIM 64
#define NN 4096
// 0.125 * log2(e) folded into Wq; exp computed as 2^x
#define QSCALE 0.18033688011112042f
#define MBIAS  -14426.950408889634f

typedef __bf16 bfx8 __attribute__((ext_vector_type(8)));
typedef __bf16 bf2  __attribute__((ext_vector_type(2)));
typedef float  f32x4 __attribute__((ext_vector_type(4)));
typedef int    i32x4 __attribute__((ext_vector_type(4)));

__device__ inline ushort f2bf(float f) {
  return __builtin_bit_cast(ushort, (__bf16)f);   // native RNE cvt (packs to v_cvt_pk)
}

__device__ __forceinline__ void gload_lds16(const void* g, void* l) {
  __builtin_amdgcn_global_load_lds(
      (const __attribute__((address_space(1))) void*)g,
      (__attribute__((address_space(3))) void*)l, 16, 0, 0);
}

__device__ __forceinline__ void swap32(int& a, int& b) {
  asm("v_permlane32_swap_b32 %0, %1" : "+v"(a), "+v"(b));
}
__device__ __forceinline__ void swap16(int& a, int& b) {
  asm("v_permlane16_swap_b32 %0, %1" : "+v"(a), "+v"(b));
}

// ---------------- weight convert fp32 -> bf16 (Q part pre-scaled) ----------------
__global__ __launch_bounds__(256)
void convert_w(const float* __restrict__ Wqkv, const float* __restrict__ Wproj,
               ushort* __restrict__ Wq, ushort* __restrict__ Wp) {
    const int n1 = (1536*CC)/4;
    const int n2 = (CC*CC)/4;
    int i = blockIdx.x*256 + threadIdx.x;
    if (i < n1) {
        float4 v = *(const float4*)(&Wqkv[(size_t)i*4]);
        if (i < 65536) { v.x*=QSCALE; v.y*=QSCALE; v.z*=QSCALE; v.w*=QSCALE; }
        ushort4 o; o.x=f2bf(v.x); o.y=f2bf(v.y); o.z=f2bf(v.z); o.w=f2bf(v.w);
        *(ushort4*)(&Wq[(size_t)i*4]) = o;
    } else if (i < n1+n2) {
        int j = i - n1;
        float4 v = *(const float4*)(&Wproj[(size_t)j*4]);
        ushort4 o; o.x=f2bf(v.x); o.y=f2bf(v.y); o.z=f2bf(v.z); o.w=f2bf(v.w);
        *(ushort4*)(&Wp[(size_t)j*4]) = o;
    }
}

// ---------------- transpose x [B][C][N] f32 -> xT [B][N][C] bf16 ----------------
__global__ __launch_bounds__(256)
void transpose_x(const float* __restrict__ x, ushort* __restrict__ xT) {
    const int bn = blockIdx.x, bc = blockIdx.y, b = blockIdx.z;
    const int t = threadIdx.x;
    __shared__ float T[64][65];
    const int n0 = bn*64, c0 = bc*64;
    const int tc = t >> 4, tn4 = (t & 15) * 4;
    #pragma unroll
    for (int r = 0; r < 4; ++r) {
        int c = tc + r*16;
        float4 v = *(const float4*)(&x[((size_t)b*CC + c0 + c)*NN + n0 + tn4]);
        T[c][tn4+0] = v.x; T[c][tn4+1] = v.y; T[c][tn4+2] = v.z; T[c][tn4+3] = v.w;
    }
    __syncthreads();
    #pragma unroll
    for (int r = 0; r < 4; ++r) {
        int n = tc + r*16;
        ushort4 o;
        o.x = f2bf(T[tn4+0][n]); o.y = f2bf(T[tn4+1][n]);
        o.z = f2bf(T[tn4+2][n]); o.w = f2bf(T[tn4+3][n]);
        *(ushort4*)(&xT[((size_t)b*NN + n0 + n)*CC + c0 + tn4]) = o;
    }
}

// ---------------- QKV GEMM (bf16 MFMA) ----------------
__global__ __launch_bounds__(256)
void qkv_mfma(const ushort* __restrict__ xT, const ushort* __restrict__ Wb,
              const float* __restrict__ bias, ushort* __restrict__ qws,
              ushort* __restrict__ kws, ushort* __restrict__ vws) {
    const int bn = blockIdx.x;
    const int bo = blockIdx.y;
    const int b  = blockIdx.z;
    const int t  = threadIdx.x;
    const int w  = t >> 6, l = t & 63, g = l >> 4, m = l & 15;
    const int o0 = bo * 128, n0 = bn * 128;
    const int part = o0 >> 9;    // 0=q 1=k 2=v
    const int wr = w >> 1, wc = w & 1;

    __shared__ __align__(16) ushort Xs[128*64];
    __shared__ __align__(16) ushort Ws_[128*64];

    const ushort* xbase = xT + ((size_t)b*NN + n0)*CC;
    const ushort* wbase = Wb + (size_t)o0*CC;

    f32x4 acc[4][4];
    #pragma unroll
    for (int i=0;i<4;i++)
        #pragma unroll
        for (int j=0;j<4;j++) acc[i][j] = (f32x4){0.f,0.f,0.f,0.f};

    const ushort* R = (part < 2) ? Xs  : Ws_;
    const ushort* Cc = (part < 2) ? Ws_ : Xs;

    for (int k0 = 0; k0 < CC; k0 += 64) {
        #pragma unroll
        for (int it = 0; it < 4; ++it) {
            int c16 = (it*4 + w)*64 + l;
            int row = c16 >> 3;
            int gch = (c16 & 7) ^ (row & 7);
            gload_lds16(xbase + (size_t)row*CC + k0 + gch*8, Xs  + c16*8);
            gload_lds16(wbase + (size_t)row*CC + k0 + gch*8, Ws_ + c16*8);
        }
        __syncthreads();
        __builtin_amdgcn_s_setprio(1);
        #pragma unroll
        for (int kc = 0; kc < 2; ++kc) {
            bfx8 ra[4], cb[4];
            #pragma unroll
            for (int f = 0; f < 4; ++f) {
                int rrow = wr*64 + f*16 + m;
                ra[f] = *(const bfx8*)(R  + (rrow*8 + ((kc*4+g) ^ (rrow&7)))*8);
                int crow = wc*64 + f*16 + m;
                cb[f] = *(const bfx8*)(Cc + (crow*8 + ((kc*4+g) ^ (crow&7)))*8);
            }
            #pragma unroll
            for (int i = 0; i < 4; ++i)
                #pragma unroll
                for (int j = 0; j < 4; ++j)
                    acc[i][j] = __builtin_amdgcn_mfma_f32_16x16x32_bf16(ra[i], cb[j], acc[i][j], 0, 0, 0);
        }
        __builtin_amdgcn_s_setprio(0);
        __syncthreads();
    }

    if (part < 2) {
        ushort* dst = (part == 0) ? qws : kws;
        const float bs = (part == 0) ? QSCALE : 1.f;
        #pragma unroll
        for (int j = 0; j < 4; ++j) {
            int o = o0 + wc*64 + j*16 + m;
            int ol = o & 511;
            int h = ol >> 6, d = ol & 63;
            float bv = bias[o] * bs;
            ushort* dp = dst + ((size_t)b*NH + h)*(size_t)NN*DDIM + d;
            #pragma unroll
            for (int i = 0; i < 4; ++i)
                #pragma unroll
                for (int r = 0; r < 4; ++r) {
                    int n = n0 + wr*64 + i*16 + g*4 + r;
                    dp[(size_t)n*DDIM] = f2bf(acc[i][j][r] + bv);
                }
        }
    } else {
        #pragma unroll
        for (int i = 0; i < 4; ++i)
            #pragma unroll
            for (int r = 0; r < 4; ++r) {
                int o = o0 + wr*64 + i*16 + g*4 + r;
                int vo = o - 1024;
                int h = vo >> 6, d = vo & 63;
                float bv = bias[o];
                ushort* dp = vws + (((size_t)b*NH + h)*DDIM + d)*NN;
                #pragma unroll
                for (int j = 0; j < 4; ++j) {
                    int n = n0 + wc*64 + j*16 + m;
                    dp[n] = f2bf(acc[i][j][r] + bv);
                }
            }
    }
}

// ---------------- Flash attention (swapped-QK^T, in-register softmax) ----------------
__global__ __launch_bounds__(256, 4)
void attn_mfma(const ushort* __restrict__ qw, const ushort* __restrict__ kw,
               const ushort* __restrict__ vw, const float* __restrict__ mask,
               ushort* __restrict__ aob) {
    const int qt = blockIdx.x, h = blockIdx.y, b = blockIdx.z;
    const int t = threadIdx.x;
    const int w = t >> 6, l = t & 63, g = l >> 4, m = l & 15;
    const int n0 = qt * 64;
    const size_t bh = (size_t)b * NH + h;
    const ushort* qp = qw + bh * (size_t)NN * DDIM;
    const ushort* kp = kw + bh * (size_t)NN * DDIM;
    const ushort* vp = vw + bh * (size_t)DDIM * NN;

    __shared__ __align__(16) ushort Ks[2][64*64];   // [key][d] chunk-swizzled
    __shared__ __align__(16) ushort Vs[2][64*64];   // [d][key] chunk-swizzled
    __shared__ float mb[2][64];

    // Q fragment (B-operand): lane (g,m) -> Q[q=m][d=kc*32+g*8..+7]
    bfx8 qf[2];
    #pragma unroll
    for (int kc = 0; kc < 2; ++kc)
        qf[kc] = *(const bfx8*)(qp + (size_t)(n0 + w*16 + m)*DDIM + kc*32 + g*8);

    f32x4 o[4];
    #pragma unroll
    for (int f=0; f<4; ++f) o[f] = (f32x4){0.f,0.f,0.f,0.f};
    float m_run = -1e30f;   // per-lane: softmax state for q = m
    float l_part = 0.f;     // per-lane partial (keys = 4g+r mod 16)

    // ---- prologue: tile 0 -> regs -> LDS[0]; tile 1 -> regs ----
    float4 kreg0, kreg1, vreg0, vreg1;
    float mreg = 0.f;
    kreg0 = *(const float4*)(kp + (size_t)t*8);
    kreg1 = *(const float4*)(kp + (size_t)(t+256)*8);
    vreg0 = *(const float4*)(vp + (size_t)(t>>3)*NN + (t&7)*8);
    vreg1 = *(const float4*)(vp + (size_t)((t+256)>>3)*NN + ((t+256)&7)*8);
    if (t < 64) mreg = mask[(size_t)b*NN + t];
    {
        int row = t >> 3, c = t & 7;
        *(float4*)(&Ks[0][row*64 + ((c ^ (row&7))*8)]) = kreg0;
        *(float4*)(&Vs[0][row*64 + ((c ^ (row&7))*8)]) = vreg0;
        int t1 = t + 256, row1 = t1 >> 3, c1 = t1 & 7;
        *(float4*)(&Ks[0][row1*64 + ((c1 ^ (row1&7))*8)]) = kreg1;
        *(float4*)(&Vs[0][row1*64 + ((c1 ^ (row1&7))*8)]) = vreg1;
        if (t < 64) mb[0][t] = (1.f - mreg) * MBIAS;
    }
    {
        const int nb = 64;
        kreg0 = *(const float4*)(kp + (size_t)nb*DDIM + t*8);
        kreg1 = *(const float4*)(kp + (size_t)nb*DDIM + (t+256)*8);
        vreg0 = *(const float4*)(vp + (size_t)(t>>3)*NN + nb + (t&7)*8);
        vreg1 = *(const float4*)(vp + (size_t)((t+256)>>3)*NN + nb + ((t+256)&7)*8);
        if (t < 64) mreg = mask[(size_t)b*NN + nb + t];
    }

    for (int kt = 0; kt < 64; ++kt) {
        const int cur = kt & 1, nxt = cur ^ 1;
        __syncthreads();
        if (kt + 1 < 64) {   // stage tile kt+1 -> LDS[nxt]
            int row = t >> 3, c = t & 7;
            *(float4*)(&Ks[nxt][row*64 + ((c ^ (row&7))*8)]) = kreg0;
            *(float4*)(&Vs[nxt][row*64 + ((c ^ (row&7))*8)]) = vreg0;
            int t1 = t + 256, row1 = t1 >> 3, c1 = t1 & 7;
            *(float4*)(&Ks[nxt][row1*64 + ((c1 ^ (row1&7))*8)]) = kreg1;
            *(float4*)(&Vs[nxt][row1*64 + ((c1 ^ (row1&7))*8)]) = vreg1;
            if (t < 64) mb[nxt][t] = (1.f - mreg) * MBIAS;
        }
        if (kt + 2 < 64) {   // issue loads tile kt+2
            const int nb = (kt + 2) * 64;
            kreg0 = *(const float4*)(kp + (size_t)nb*DDIM + t*8);
            kreg1 = *(const float4*)(kp + (size_t)nb*DDIM + (t+256)*8);
            vreg0 = *(const float4*)(vp + (size_t)(t>>3)*NN + nb + (t&7)*8);
            vreg1 = *(const float4*)(vp + (size_t)((t+256)>>3)*NN + nb + ((t+256)&7)*8);
            if (t < 64) mreg = mask[(size_t)b*NN + nb + t];
        }

        // ---- S^T = K Q^T : lane (g,m) holds S[key=16f+4g+r][q=m] ----
        f32x4 sa[4];
        #pragma unroll
        for (int f=0; f<4; ++f) sa[f] = (f32x4){0.f,0.f,0.f,0.f};
        __builtin_amdgcn_s_setprio(1);
        #pragma unroll
        for (int kc=0; kc<2; ++kc)
            #pragma unroll
            for (int f=0; f<4; ++f) {
                int row = f*16 + m;
                bfx8 kf = *(const bfx8*)(&Ks[cur][row*64 + ((kc*32 + g*8) ^ ((row&7)*8))]);
                sa[f] = __builtin_amdgcn_mfma_f32_16x16x32_bf16(kf, qf[kc], sa[f], 0, 0, 0);
            }
        __builtin_amdgcn_s_setprio(0);

        // ---- bias + in-register online softmax (all state per-lane, q=m) ----
        float sv[4][4];
        #pragma unroll
        for (int f=0; f<4; ++f) {
            float4 mbv = *(const float4*)(&mb[cur][f*16 + 4*g]);
            sv[f][0] = sa[f][0] + mbv.x;
            sv[f][1] = sa[f][1] + mbv.y;
            sv[f][2] = sa[f][2] + mbv.z;
            sv[f][3] = sa[f][3] + mbv.w;
        }
        float tmax = sv[0][0];
        #pragma unroll
        for (int f=0; f<4; ++f)
            #pragma unroll
            for (int r=0; r<4; ++r) tmax = fmaxf(tmax, sv[f][r]);
        tmax = fmaxf(tmax, __shfl_xor(tmax, 16));
        tmax = fmaxf(tmax, __shfl_xor(tmax, 32));

        if (__any(tmax > m_run + 8.f)) {   // rare rescale (T13 defer-max)
            float mnew = fmaxf(m_run, tmax);
            float alpha = __builtin_amdgcn_exp2f(m_run - mnew);
            m_run = mnew;
            l_part *= alpha;
            float ar[4];
            #pragma unroll
            for (int r=0; r<4; ++r) ar[r] = __shfl(alpha, 4*g + r);
            #pragma unroll
            for (int f=0; f<4; ++f)
                #pragma unroll
                for (int r=0; r<4; ++r) o[f][r] *= ar[r];
        }

        float pv_[4][4];
        float tsum = 0.f;
        #pragma unroll
        for (int f=0; f<4; ++f)
            #pragma unroll
            for (int r=0; r<4; ++r) {
                float p = __builtin_amdgcn_exp2f(sv[f][r] - m_run);
                pv_[f][r] = p;
                tsum += p;
            }
        l_part += tsum;

        // ---- pack P to bf16 pairs: u[f][p] = keys (16f+4g+2p, +1), q=m ----
        int u[4][2];
        #pragma unroll
        for (int f=0; f<4; ++f)
            #pragma unroll
            for (int pp=0; pp<2; ++pp) {
                bf2 tpk = { (__bf16)pv_[f][2*pp], (__bf16)pv_[f][2*pp+1] };
                u[f][pp] = __builtin_bit_cast(int, tpk);
            }
        // ---- in-register transpose to PV A-frag (regbits key4->lane5, key3->lane4) ----
        #pragma unroll
        for (int pp=0; pp<2; ++pp) { swap32(u[0][pp], u[1][pp]); swap32(u[2][pp], u[3][pp]); }
        #pragma unroll
        for (int pp=0; pp<2; ++pp) { swap16(u[0][pp], u[1][pp]); swap16(u[2][pp], u[3][pp]); }
        bfx8 pa[2];
        pa[0] = __builtin_bit_cast(bfx8, (i32x4){u[0][0], u[0][1], u[1][0], u[1][1]});
        pa[1] = __builtin_bit_cast(bfx8, (i32x4){u[2][0], u[2][1], u[3][0], u[3][1]});

        // ---- O += P V : lane (g,m) holds O[q=4g+r][d=16f+m] ----
        __builtin_amdgcn_s_setprio(1);
        #pragma unroll
        for (int kc=0; kc<2; ++kc)
            #pragma unroll
            for (int f=0; f<4; ++f) {
                int row = f*16 + m;
                bfx8 vf = *(const bfx8*)(&Vs[cur][row*64 + ((kc*32 + g*8) ^ ((row&7)*8))]);
                o[f] = __builtin_amdgcn_mfma_f32_16x16x32_bf16(pa[kc], vf, o[f], 0, 0, 0);
            }
        __builtin_amdgcn_s_setprio(0);
    }

    // ---- finish l, normalize, store bf16 [B][N][C] ----
    float l_tot = l_part + __shfl_xor(l_part, 16);
    l_tot += __shfl_xor(l_tot, 32);
    float linv = 1.f / l_tot;
    float lr[4];
    #pragma unroll
    for (int r=0; r<4; ++r) lr[r] = __shfl(linv, 4*g + r);
    #pragma unroll
    for (int f=0; f<4; ++f)
        #pragma unroll
        for (int r=0; r<4; ++r)
            aob[((size_t)b*NN + n0 + w*16 + 4*g + r)*CC + h*DDIM + f*16 + m] = f2bf(o[f][r] * lr[r]);
}

// ---------------- Proj GEMM (bf16 MFMA, fp32 out) ----------------
__global__ __launch_bounds__(256)
void proj_mfma(const ushort* __restrict__ aob, const ushort* __restrict__ Wp,
               const float* __restrict__ bias, float* __restrict__ out) {
    const int bn = blockIdx.x;
    const int bo = blockIdx.y;
    const int b  = blockIdx.z;
    const int t  = threadIdx.x;
    const int w  = t >> 6, l = t & 63, g = l >> 4, m = l & 15;
    const int o0 = bo * 128, n0 = bn * 128;
    const int wr = w >> 1, wc = w & 1;

    __shared__ __align__(16) ushort As_[128*64];
    __shared__ __align__(16) ushort Ws_[128*64];

    const ushort* abase = aob + ((size_t)b*NN + n0)*CC;
    const ushort* wbase = Wp + (size_t)o0*CC;

    f32x4 acc[4][4];
    #pragma unroll
    for (int i=0;i<4;i++)
        #pragma unroll
        for (int j=0;j<4;j++) acc[i][j] = (f32x4){0.f,0.f,0.f,0.f};

    for (int k0 = 0; k0 < CC; k0 += 64) {
        #pragma unroll
        for (int it = 0; it < 4; ++it) {
            int c16 = (it*4 + w)*64 + l;
            int row = c16 >> 3;
            int gch = (c16 & 7) ^ (row & 7);
            gload_lds16(abase + (size_t)row*CC + k0 + gch*8, As_ + c16*8);
            gload_lds16(wbase + (size_t)row*CC + k0 + gch*8, Ws_ + c16*8);
        }
        __syncthreads();
        __builtin_amdgcn_s_setprio(1);
        #pragma unroll
        for (int kc = 0; kc < 2; ++kc) {
            bfx8 ra[4], cb[4];
            #pragma unroll
            for (int f = 0; f < 4; ++f) {
                int rrow = wr*64 + f*16 + m;
                ra[f] = *(const bfx8*)(Ws_ + (rrow*8 + ((kc*4+g) ^ (rrow&7)))*8);
                int crow = wc*64 + f*16 + m;
                cb[f] = *(const bfx8*)(As_ + (crow*8 + ((kc*4+g) ^ (crow&7)))*8);
            }
            #pragma unroll
            for (int i = 0; i < 4; ++i)
                #pragma unroll
                for (int j = 0; j < 4; ++j)
                    acc[i][j] = __builtin_amdgcn_mfma_f32_16x16x32_bf16(ra[i], cb[j], acc[i][j], 0, 0, 0);
        }
        __builtin_amdgcn_s_setprio(0);
        __syncthreads();
    }
    #pragma unroll
    for (int i = 0; i < 4; ++i)
        #pragma unroll
        for (int r = 0; r < 4; ++r) {
            int o = o0 + wr*64 + i*16 + g*4 + r;
            float bv = bias[o];
            float* dp = out + ((size_t)b*CC + o)*NN;
            #pragma unroll
            for (int j = 0; j < 4; ++j) {
                int n = n0 + wc*64 + j*16 + m;
                dp[n] = acc[i][j][r] + bv;
            }
        }
}

extern "C" void kernel_launch(void* const* d_in, const int* in_sizes, int n_in,
                              void* d_out, int out_size, void* d_ws, size_t ws_size,
                              hipStream_t stream) {
    const float* x     = (const float*)d_in[0];
    const float* mask  = (const float*)d_in[1];
    const float* Wqkv  = (const float*)d_in[2];
    const float* bqkv  = (const float*)d_in[3];
    const float* Wproj = (const float*)d_in[4];
    const float* bproj = (const float*)d_in[5];
    float* out = (float*)d_out;

    const size_t per = (size_t)BB*NH*NN*DDIM;
    ushort* qws = (ushort*)d_ws;
    ushort* kws = qws + per;
    ushort* vws = kws + per;
    ushort* xTb = vws + per;
    ushort* aob = xTb + per;
    ushort* Wqb = aob + per;
    ushort* Wpb = Wqb + (size_t)1536*CC;

    convert_w<<<dim3(1024), 256, 0, stream>>>(Wqkv, Wproj, Wqb, Wpb);
    transpose_x<<<dim3(64, 8, BB), 256, 0, stream>>>(x, xTb);
    qkv_mfma<<<dim3(32, 12, BB), 256, 0, stream>>>(xTb, Wqb, bqkv, qws, kws, vws);
    attn_mfma<<<dim3(64, NH, BB), 256, 0, stream>>>(qws, kws, vws, mask, aob);
    proj_mfma<<<dim3(32, 4, BB), 256, 0, stream>>>(aob, Wpb, bproj, out);
}

// Round 5
// 215.031 us; speedup vs baseline: 10.3188x; 1.0432x over previous
//
#include <hip/hip_runtime.h>

#define BB 2
#define CC 512
#define NH 8
#define DDIM 64
#define NN 4096
// 0.125 * log2(e) folded into Wq; exp computed as 2^x
#define QSCALE 0.18033688011112042f
#define MBIAS  -14426.950408889634f

typedef __bf16 bfx8 __attribute__((ext_vector_type(8)));
typedef __bf16 bf2  __attribute__((ext_vector_type(2)));
typedef float  f32x4 __attribute__((ext_vector_type(4)));
typedef int    i32x4 __attribute__((ext_vector_type(4)));

__device__ inline ushort f2bf(float f) {
  return __builtin_bit_cast(ushort, (__bf16)f);
}

__device__ __forceinline__ void gload_lds16(const void* g, void* l) {
  __builtin_amdgcn_global_load_lds(
      (const __attribute__((address_space(1))) void*)g,
      (__attribute__((address_space(3))) void*)l, 16, 0, 0);
}

__device__ __forceinline__ void swap32(int& a, int& b) {
  asm("v_permlane32_swap_b32 %0, %1" : "+v"(a), "+v"(b));
}
__device__ __forceinline__ void swap16(int& a, int& b) {
  asm("v_permlane16_swap_b32 %0, %1" : "+v"(a), "+v"(b));
}

// ---------------- weight convert fp32 -> bf16 (Q part pre-scaled) ----------------
__global__ __launch_bounds__(256)
void convert_w(const float* __restrict__ Wqkv, const float* __restrict__ Wproj,
               ushort* __restrict__ Wq, ushort* __restrict__ Wp) {
    const int n1 = (1536*CC)/4;
    const int n2 = (CC*CC)/4;
    int i = blockIdx.x*256 + threadIdx.x;
    if (i < n1) {
        float4 v = *(const float4*)(&Wqkv[(size_t)i*4]);
        if (i < 65536) { v.x*=QSCALE; v.y*=QSCALE; v.z*=QSCALE; v.w*=QSCALE; }
        ushort4 o; o.x=f2bf(v.x); o.y=f2bf(v.y); o.z=f2bf(v.z); o.w=f2bf(v.w);
        *(ushort4*)(&Wq[(size_t)i*4]) = o;
    } else if (i < n1+n2) {
        int j = i - n1;
        float4 v = *(const float4*)(&Wproj[(size_t)j*4]);
        ushort4 o; o.x=f2bf(v.x); o.y=f2bf(v.y); o.z=f2bf(v.z); o.w=f2bf(v.w);
        *(ushort4*)(&Wp[(size_t)j*4]) = o;
    }
}

// ---------------- transpose x [B][C][N] f32 -> xT [B][N][C] bf16 ----------------
__global__ __launch_bounds__(256)
void transpose_x(const float* __restrict__ x, ushort* __restrict__ xT) {
    const int bn = blockIdx.x, bc = blockIdx.y, b = blockIdx.z;
    const int t = threadIdx.x;
    __shared__ float T[64][65];
    const int n0 = bn*64, c0 = bc*64;
    const int tc = t >> 4, tn4 = (t & 15) * 4;
    #pragma unroll
    for (int r = 0; r < 4; ++r) {
        int c = tc + r*16;
        float4 v = *(const float4*)(&x[((size_t)b*CC + c0 + c)*NN + n0 + tn4]);
        T[c][tn4+0] = v.x; T[c][tn4+1] = v.y; T[c][tn4+2] = v.z; T[c][tn4+3] = v.w;
    }
    __syncthreads();
    #pragma unroll
    for (int r = 0; r < 4; ++r) {
        int n = tc + r*16;
        ushort4 o;
        o.x = f2bf(T[tn4+0][n]); o.y = f2bf(T[tn4+1][n]);
        o.z = f2bf(T[tn4+2][n]); o.w = f2bf(T[tn4+3][n]);
        *(ushort4*)(&xT[((size_t)b*NN + n0 + n)*CC + c0 + tn4]) = o;
    }
}

// ---------------- QKV GEMM (bf16 MFMA) ----------------
__global__ __launch_bounds__(256)
void qkv_mfma(const ushort* __restrict__ xT, const ushort* __restrict__ Wb,
              const float* __restrict__ bias, ushort* __restrict__ qws,
              ushort* __restrict__ kws, ushort* __restrict__ vws) {
    const int bn = blockIdx.x;
    const int bo = blockIdx.y;
    const int b  = blockIdx.z;
    const int t  = threadIdx.x;
    const int w  = t >> 6, l = t & 63, g = l >> 4, m = l & 15;
    const int o0 = bo * 128, n0 = bn * 128;
    const int part = o0 >> 9;    // 0=q 1=k 2=v
    const int wr = w >> 1, wc = w & 1;

    __shared__ __align__(16) ushort Xs[128*64];
    __shared__ __align__(16) ushort Ws_[128*64];

    const ushort* xbase = xT + ((size_t)b*NN + n0)*CC;
    const ushort* wbase = Wb + (size_t)o0*CC;

    f32x4 acc[4][4];
    #pragma unroll
    for (int i=0;i<4;i++)
        #pragma unroll
        for (int j=0;j<4;j++) acc[i][j] = (f32x4){0.f,0.f,0.f,0.f};

    const ushort* R = (part < 2) ? Xs  : Ws_;
    const ushort* Cc = (part < 2) ? Ws_ : Xs;

    for (int k0 = 0; k0 < CC; k0 += 64) {
        #pragma unroll
        for (int it = 0; it < 4; ++it) {
            int c16 = (it*4 + w)*64 + l;
            int row = c16 >> 3;
            int gch = (c16 & 7) ^ (row & 7);
            gload_lds16(xbase + (size_t)row*CC + k0 + gch*8, Xs  + c16*8);
            gload_lds16(wbase + (size_t)row*CC + k0 + gch*8, Ws_ + c16*8);
        }
        __syncthreads();
        __builtin_amdgcn_s_setprio(1);
        #pragma unroll
        for (int kc = 0; kc < 2; ++kc) {
            bfx8 ra[4], cb[4];
            #pragma unroll
            for (int f = 0; f < 4; ++f) {
                int rrow = wr*64 + f*16 + m;
                ra[f] = *(const bfx8*)(R  + (rrow*8 + ((kc*4+g) ^ (rrow&7)))*8);
                int crow = wc*64 + f*16 + m;
                cb[f] = *(const bfx8*)(Cc + (crow*8 + ((kc*4+g) ^ (crow&7)))*8);
            }
            #pragma unroll
            for (int i = 0; i < 4; ++i)
                #pragma unroll
                for (int j = 0; j < 4; ++j)
                    acc[i][j] = __builtin_amdgcn_mfma_f32_16x16x32_bf16(ra[i], cb[j], acc[i][j], 0, 0, 0);
        }
        __builtin_amdgcn_s_setprio(0);
        __syncthreads();
    }

    if (part < 2) {
        // rows(A)=n, cols(B)=o. dst [bh][n][d]; h fixed per thread, d = j*16+m.
        ushort* dst = (part == 0) ? qws : kws;
        const float bs = (part == 0) ? QSCALE : 1.f;
        const int h = ((o0 & 511) >> 6) + wc;
        float bvj[4];
        #pragma unroll
        for (int j = 0; j < 4; ++j) bvj[j] = bias[o0 + wc*64 + j*16 + m] * bs;
        ushort* base = dst + ((size_t)b*NH + h)*(size_t)NN*DDIM;
        #pragma unroll
        for (int i = 0; i < 4; ++i)
            #pragma unroll
            for (int r = 0; r < 4; ++r) {
                int n = n0 + wr*64 + i*16 + g*4 + r;
                ushort* rowp = base + (size_t)n*DDIM;
                #pragma unroll
                for (int j = 0; j < 4; ++j)
                    rowp[j*16 + m] = f2bf(acc[i][j][r] + bvj[j]);
            }
    } else {
        #pragma unroll
        for (int i = 0; i < 4; ++i)
            #pragma unroll
            for (int r = 0; r < 4; ++r) {
                int o = o0 + wr*64 + i*16 + g*4 + r;
                int vo = o - 1024;
                int h = vo >> 6, d = vo & 63;
                float bv = bias[o];
                ushort* dp = vws + (((size_t)b*NH + h)*DDIM + d)*NN;
                #pragma unroll
                for (int j = 0; j < 4; ++j) {
                    int n = n0 + wc*64 + j*16 + m;
                    dp[n] = f2bf(acc[i][j][r] + bv);
                }
            }
    }
}

// ---------------- Flash attention (swapped-QK^T, 32 q/wave, in-reg softmax) ----------------
__global__ __launch_bounds__(256, 2)
void attn_mfma(const ushort* __restrict__ qw, const ushort* __restrict__ kw,
               const ushort* __restrict__ vw, const float* __restrict__ mask,
               ushort* __restrict__ aob) {
    const int qt = blockIdx.x, h = blockIdx.y, b = blockIdx.z;
    const int t = threadIdx.x;
    const int w = t >> 6, l = t & 63, g = l >> 4, m = l & 15;
    const int n0 = qt * 128;                 // 128 q rows per block, 32 per wave
    const size_t bh = (size_t)b * NH + h;
    const ushort* qp = qw + bh * (size_t)NN * DDIM;
    const ushort* kp = kw + bh * (size_t)NN * DDIM;
    const ushort* vp = vw + bh * (size_t)DDIM * NN;

    __shared__ __align__(16) ushort Ks[2][64*64];   // [key][d] chunk-swizzled
    __shared__ __align__(16) ushort Vs[2][64*64];   // [d][key] chunk-swizzled
    __shared__ float mb[2][64];

    // Q fragments (B-operand): qidx in {0,1}: q = n0 + w*32 + qidx*16 + m
    bfx8 qf[2][2];
    #pragma unroll
    for (int qi = 0; qi < 2; ++qi)
        #pragma unroll
        for (int kc = 0; kc < 2; ++kc)
            qf[qi][kc] = *(const bfx8*)(qp + (size_t)(n0 + w*32 + qi*16 + m)*DDIM + kc*32 + g*8);

    f32x4 o[2][4];
    #pragma unroll
    for (int qi=0; qi<2; ++qi)
        #pragma unroll
        for (int f=0; f<4; ++f) o[qi][f] = (f32x4){0.f,0.f,0.f,0.f};
    float m_run[2] = {-1e30f, -1e30f};
    float l_part[2] = {0.f, 0.f};

    // ---- prologue ----
    float4 kreg0, kreg1, vreg0, vreg1;
    float mreg = 0.f;
    kreg0 = *(const float4*)(kp + (size_t)t*8);
    kreg1 = *(const float4*)(kp + (size_t)(t+256)*8);
    vreg0 = *(const float4*)(vp + (size_t)(t>>3)*NN + (t&7)*8);
    vreg1 = *(const float4*)(vp + (size_t)((t+256)>>3)*NN + ((t+256)&7)*8);
    if (t < 64) mreg = mask[(size_t)b*NN + t];
    {
        int row = t >> 3, c = t & 7;
        *(float4*)(&Ks[0][row*64 + ((c ^ (row&7))*8)]) = kreg0;
        *(float4*)(&Vs[0][row*64 + ((c ^ (row&7))*8)]) = vreg0;
        int t1 = t + 256, row1 = t1 >> 3, c1 = t1 & 7;
        *(float4*)(&Ks[0][row1*64 + ((c1 ^ (row1&7))*8)]) = kreg1;
        *(float4*)(&Vs[0][row1*64 + ((c1 ^ (row1&7))*8)]) = vreg1;
        if (t < 64) mb[0][t] = (1.f - mreg) * MBIAS;
    }
    {
        const int nb = 64;
        kreg0 = *(const float4*)(kp + (size_t)nb*DDIM + t*8);
        kreg1 = *(const float4*)(kp + (size_t)nb*DDIM + (t+256)*8);
        vreg0 = *(const float4*)(vp + (size_t)(t>>3)*NN + nb + (t&7)*8);
        vreg1 = *(const float4*)(vp + (size_t)((t+256)>>3)*NN + nb + ((t+256)&7)*8);
        if (t < 64) mreg = mask[(size_t)b*NN + nb + t];
    }

    for (int kt = 0; kt < 64; ++kt) {
        const int cur = kt & 1, nxt = cur ^ 1;
        __syncthreads();
        if (kt + 1 < 64) {
            int row = t >> 3, c = t & 7;
            *(float4*)(&Ks[nxt][row*64 + ((c ^ (row&7))*8)]) = kreg0;
            *(float4*)(&Vs[nxt][row*64 + ((c ^ (row&7))*8)]) = vreg0;
            int t1 = t + 256, row1 = t1 >> 3, c1 = t1 & 7;
            *(float4*)(&Ks[nxt][row1*64 + ((c1 ^ (row1&7))*8)]) = kreg1;
            *(float4*)(&Vs[nxt][row1*64 + ((c1 ^ (row1&7))*8)]) = vreg1;
            if (t < 64) mb[nxt][t] = (1.f - mreg) * MBIAS;
        }
        if (kt + 2 < 64) {
            const int nb = (kt + 2) * 64;
            kreg0 = *(const float4*)(kp + (size_t)nb*DDIM + t*8);
            kreg1 = *(const float4*)(kp + (size_t)nb*DDIM + (t+256)*8);
            vreg0 = *(const float4*)(vp + (size_t)(t>>3)*NN + nb + (t&7)*8);
            vreg1 = *(const float4*)(vp + (size_t)((t+256)>>3)*NN + nb + ((t+256)&7)*8);
            if (t < 64) mreg = mask[(size_t)b*NN + nb + t];
        }

        // ---- S^T = K Q^T : lane (g,m) holds S[key=16f+4g+r][q=m] per qidx ----
        f32x4 sa[2][4];
        #pragma unroll
        for (int qi=0; qi<2; ++qi)
            #pragma unroll
            for (int f=0; f<4; ++f) sa[qi][f] = (f32x4){0.f,0.f,0.f,0.f};
        __builtin_amdgcn_s_setprio(1);
        #pragma unroll
        for (int kc=0; kc<2; ++kc)
            #pragma unroll
            for (int f=0; f<4; ++f) {
                int row = f*16 + m;
                bfx8 kf = *(const bfx8*)(&Ks[cur][row*64 + ((kc*32 + g*8) ^ ((row&7)*8))]);
                #pragma unroll
                for (int qi=0; qi<2; ++qi)
                    sa[qi][f] = __builtin_amdgcn_mfma_f32_16x16x32_bf16(kf, qf[qi][kc], sa[qi][f], 0, 0, 0);
            }
        __builtin_amdgcn_s_setprio(0);

        // mask bias (shared across qidx)
        float4 mbv[4];
        #pragma unroll
        for (int f=0; f<4; ++f) mbv[f] = *(const float4*)(&mb[cur][f*16 + 4*g]);

        bfx8 pa[2][2];
        #pragma unroll
        for (int qi=0; qi<2; ++qi) {
            float sv[4][4];
            #pragma unroll
            for (int f=0; f<4; ++f) {
                sv[f][0] = sa[qi][f][0] + mbv[f].x;
                sv[f][1] = sa[qi][f][1] + mbv[f].y;
                sv[f][2] = sa[qi][f][2] + mbv[f].z;
                sv[f][3] = sa[qi][f][3] + mbv[f].w;
            }
            float tmax = sv[0][0];
            #pragma unroll
            for (int f=0; f<4; ++f)
                #pragma unroll
                for (int r=0; r<4; ++r) tmax = fmaxf(tmax, sv[f][r]);
            tmax = fmaxf(tmax, __shfl_xor(tmax, 16));
            tmax = fmaxf(tmax, __shfl_xor(tmax, 32));

            if (__any(tmax > m_run[qi] + 8.f)) {
                float mnew = fmaxf(m_run[qi], tmax);
                float alpha = __builtin_amdgcn_exp2f(m_run[qi] - mnew);
                m_run[qi] = mnew;
                l_part[qi] *= alpha;
                float ar[4];
                #pragma unroll
                for (int r=0; r<4; ++r) ar[r] = __shfl(alpha, 4*g + r);
                #pragma unroll
                for (int f=0; f<4; ++f)
                    #pragma unroll
                    for (int r=0; r<4; ++r) o[qi][f][r] *= ar[r];
            }

            float pv_[4][4];
            float tsum = 0.f;
            #pragma unroll
            for (int f=0; f<4; ++f)
                #pragma unroll
                for (int r=0; r<4; ++r) {
                    float p = __builtin_amdgcn_exp2f(sv[f][r] - m_run[qi]);
                    pv_[f][r] = p;
                    tsum += p;
                }
            l_part[qi] += tsum;

            int u[4][2];
            #pragma unroll
            for (int f=0; f<4; ++f)
                #pragma unroll
                for (int pp=0; pp<2; ++pp) {
                    bf2 tpk = { (__bf16)pv_[f][2*pp], (__bf16)pv_[f][2*pp+1] };
                    u[f][pp] = __builtin_bit_cast(int, tpk);
                }
            #pragma unroll
            for (int pp=0; pp<2; ++pp) { swap32(u[0][pp], u[1][pp]); swap32(u[2][pp], u[3][pp]); }
            #pragma unroll
            for (int pp=0; pp<2; ++pp) { swap16(u[0][pp], u[1][pp]); swap16(u[2][pp], u[3][pp]); }
            pa[qi][0] = __builtin_bit_cast(bfx8, (i32x4){u[0][0], u[0][1], u[1][0], u[1][1]});
            pa[qi][1] = __builtin_bit_cast(bfx8, (i32x4){u[2][0], u[2][1], u[3][0], u[3][1]});
        }

        // ---- O += P V (V fragment reused across qidx) ----
        __builtin_amdgcn_s_setprio(1);
        #pragma unroll
        for (int kc=0; kc<2; ++kc)
            #pragma unroll
            for (int f=0; f<4; ++f) {
                int row = f*16 + m;
                bfx8 vf = *(const bfx8*)(&Vs[cur][row*64 + ((kc*32 + g*8) ^ ((row&7)*8))]);
                #pragma unroll
                for (int qi=0; qi<2; ++qi)
                    o[qi][f] = __builtin_amdgcn_mfma_f32_16x16x32_bf16(pa[qi][kc], vf, o[qi][f], 0, 0, 0);
            }
        __builtin_amdgcn_s_setprio(0);
    }

    // ---- finish l, normalize, store bf16 [B][N][C] ----
    #pragma unroll
    for (int qi=0; qi<2; ++qi) {
        float l_tot = l_part[qi] + __shfl_xor(l_part[qi], 16);
        l_tot += __shfl_xor(l_tot, 32);
        float linv = 1.f / l_tot;
        float lr[4];
        #pragma unroll
        for (int r=0; r<4; ++r) lr[r] = __shfl(linv, 4*g + r);
        #pragma unroll
        for (int f=0; f<4; ++f)
            #pragma unroll
            for (int r=0; r<4; ++r)
                aob[((size_t)b*NN + n0 + w*32 + qi*16 + 4*g + r)*CC + h*DDIM + f*16 + m] = f2bf(o[qi][f][r] * lr[r]);
    }
}

// ---------------- Proj GEMM (bf16 MFMA, fp32 out) ----------------
__global__ __launch_bounds__(256)
void proj_mfma(const ushort* __restrict__ aob, const ushort* __restrict__ Wp,
               const float* __restrict__ bias, float* __restrict__ out) {
    const int bn = blockIdx.x;
    const int bo = blockIdx.y;
    const int b  = blockIdx.z;
    const int t  = threadIdx.x;
    const int w  = t >> 6, l = t & 63, g = l >> 4, m = l & 15;
    const int o0 = bo * 128, n0 = bn * 128;
    const int wr = w >> 1, wc = w & 1;

    __shared__ __align__(16) ushort As_[128*64];
    __shared__ __align__(16) ushort Ws_[128*64];

    const ushort* abase = aob + ((size_t)b*NN + n0)*CC;
    const ushort* wbase = Wp + (size_t)o0*CC;

    f32x4 acc[4][4];
    #pragma unroll
    for (int i=0;i<4;i++)
        #pragma unroll
        for (int j=0;j<4;j++) acc[i][j] = (f32x4){0.f,0.f,0.f,0.f};

    for (int k0 = 0; k0 < CC; k0 += 64) {
        #pragma unroll
        for (int it = 0; it < 4; ++it) {
            int c16 = (it*4 + w)*64 + l;
            int row = c16 >> 3;
            int gch = (c16 & 7) ^ (row & 7);
            gload_lds16(abase + (size_t)row*CC + k0 + gch*8, As_ + c16*8);
            gload_lds16(wbase + (size_t)row*CC + k0 + gch*8, Ws_ + c16*8);
        }
        __syncthreads();
        __builtin_amdgcn_s_setprio(1);
        #pragma unroll
        for (int kc = 0; kc < 2; ++kc) {
            bfx8 ra[4], cb[4];
            #pragma unroll
            for (int f = 0; f < 4; ++f) {
                int rrow = wr*64 + f*16 + m;
                ra[f] = *(const bfx8*)(Ws_ + (rrow*8 + ((kc*4+g) ^ (rrow&7)))*8);
                int crow = wc*64 + f*16 + m;
                cb[f] = *(const bfx8*)(As_ + (crow*8 + ((kc*4+g) ^ (crow&7)))*8);
            }
            #pragma unroll
            for (int i = 0; i < 4; ++i)
                #pragma unroll
                for (int j = 0; j < 4; ++j)
                    acc[i][j] = __builtin_amdgcn_mfma_f32_16x16x32_bf16(ra[i], cb[j], acc[i][j], 0, 0, 0);
        }
        __builtin_amdgcn_s_setprio(0);
        __syncthreads();
    }
    #pragma unroll
    for (int i = 0; i < 4; ++i)
        #pragma unroll
        for (int r = 0; r < 4; ++r) {
            int o = o0 + wr*64 + i*16 + g*4 + r;
            float bv = bias[o];
            float* dp = out + ((size_t)b*CC + o)*NN;
            #pragma unroll
            for (int j = 0; j < 4; ++j) {
                int n = n0 + wc*64 + j*16 + m;
                dp[n] = acc[i][j][r] + bv;
            }
        }
}

extern "C" void kernel_launch(void* const* d_in, const int* in_sizes, int n_in,
                              void* d_out, int out_size, void* d_ws, size_t ws_size,
                              hipStream_t stream) {
    const float* x     = (const float*)d_in[0];
    const float* mask  = (const float*)d_in[1];
    const float* Wqkv  = (const float*)d_in[2];
    const float* bqkv  = (const float*)d_in[3];
    const float* Wproj = (const float*)d_in[4];
    const float* bproj = (const float*)d_in[5];
    float* out = (float*)d_out;

    const size_t per = (size_t)BB*NH*NN*DDIM;
    ushort* qws = (ushort*)d_ws;
    ushort* kws = qws + per;
    ushort* vws = kws + per;
    ushort* xTb = vws + per;
    ushort* aob = xTb + per;
    ushort* Wqb = aob + per;
    ushort* Wpb = Wqb + (size_t)1536*CC;

    convert_w<<<dim3(1024), 256, 0, stream>>>(Wqkv, Wproj, Wqb, Wpb);
    transpose_x<<<dim3(64, 8, BB), 256, 0, stream>>>(x, xTb);
    qkv_mfma<<<dim3(32, 12, BB), 256, 0, stream>>>(xTb, Wqb, bqkv, qws, kws, vws);
    attn_mfma<<<dim3(32, NH, BB), 256, 0, stream>>>(qws, kws, vws, mask, aob);
    proj_mfma<<<dim3(32, 4, BB), 256, 0, stream>>>(aob, Wpb, bproj, out);
}

// Round 6
// 201.714 us; speedup vs baseline: 11.0000x; 1.0660x over previous
//
#include <hip/hip_runtime.h>

#define BB 2
#define CC 512
#define NH 8
#define DDIM 64
#define NN 4096
// 0.125 * log2(e) folded into Wq; exp computed as 2^x
#define QSCALE 0.18033688011112042f
#define MBIAS  -14426.950408889634f

typedef __bf16 bfx8 __attribute__((ext_vector_type(8)));
typedef __bf16 bf2  __attribute__((ext_vector_type(2)));
typedef float  f32x4 __attribute__((ext_vector_type(4)));
typedef int    i32x4 __attribute__((ext_vector_type(4)));
typedef ushort usx8  __attribute__((ext_vector_type(8)));

__device__ inline ushort f2bf(float f) {
  return __builtin_bit_cast(ushort, (__bf16)f);
}
__device__ inline float bf2f(ushort u) {
  return (float)__builtin_bit_cast(__bf16, u);
}

__device__ __forceinline__ void gload_lds16(const void* g, void* l) {
  __builtin_amdgcn_global_load_lds(
      (const __attribute__((address_space(1))) void*)g,
      (__attribute__((address_space(3))) void*)l, 16, 0, 0);
}

__device__ __forceinline__ void swap32(int& a, int& b) {
  asm("v_permlane32_swap_b32 %0, %1" : "+v"(a), "+v"(b));
}
__device__ __forceinline__ void swap16(int& a, int& b) {
  asm("v_permlane16_swap_b32 %0, %1" : "+v"(a), "+v"(b));
}

// ---------------- weight convert fp32 -> bf16 (Q part pre-scaled) ----------------
__global__ __launch_bounds__(256)
void convert_w(const float* __restrict__ Wqkv, const float* __restrict__ Wproj,
               ushort* __restrict__ Wq, ushort* __restrict__ Wp) {
    const int n1 = (1536*CC)/4;
    const int n2 = (CC*CC)/4;
    int i = blockIdx.x*256 + threadIdx.x;
    if (i < n1) {
        float4 v = *(const float4*)(&Wqkv[(size_t)i*4]);
        if (i < 65536) { v.x*=QSCALE; v.y*=QSCALE; v.z*=QSCALE; v.w*=QSCALE; }
        ushort4 o; o.x=f2bf(v.x); o.y=f2bf(v.y); o.z=f2bf(v.z); o.w=f2bf(v.w);
        *(ushort4*)(&Wq[(size_t)i*4]) = o;
    } else if (i < n1+n2) {
        int j = i - n1;
        float4 v = *(const float4*)(&Wproj[(size_t)j*4]);
        ushort4 o; o.x=f2bf(v.x); o.y=f2bf(v.y); o.z=f2bf(v.z); o.w=f2bf(v.w);
        *(ushort4*)(&Wp[(size_t)j*4]) = o;
    }
}

// ---------------- transpose x [B][C][N] f32 -> xT [B][N][C] bf16 ----------------
__global__ __launch_bounds__(256)
void transpose_x(const float* __restrict__ x, ushort* __restrict__ xT) {
    const int bn = blockIdx.x, bc = blockIdx.y, b = blockIdx.z;
    const int t = threadIdx.x;
    __shared__ float T[64][65];
    const int n0 = bn*64, c0 = bc*64;
    const int tc = t >> 4, tn4 = (t & 15) * 4;
    #pragma unroll
    for (int r = 0; r < 4; ++r) {
        int c = tc + r*16;
        float4 v = *(const float4*)(&x[((size_t)b*CC + c0 + c)*NN + n0 + tn4]);
        T[c][tn4+0] = v.x; T[c][tn4+1] = v.y; T[c][tn4+2] = v.z; T[c][tn4+3] = v.w;
    }
    __syncthreads();
    #pragma unroll
    for (int r = 0; r < 4; ++r) {
        int n = tc + r*16;
        ushort4 o;
        o.x = f2bf(T[tn4+0][n]); o.y = f2bf(T[tn4+1][n]);
        o.z = f2bf(T[tn4+2][n]); o.w = f2bf(T[tn4+3][n]);
        *(ushort4*)(&xT[((size_t)b*NN + n0 + n)*CC + c0 + tn4]) = o;
    }
}

// ---------------- QKV GEMM (bf16 MFMA, LDS-bounce epilogue) ----------------
__global__ __launch_bounds__(256)
void qkv_mfma(const ushort* __restrict__ xT, const ushort* __restrict__ Wb,
              const float* __restrict__ bias, ushort* __restrict__ qws,
              ushort* __restrict__ kws, ushort* __restrict__ vws) {
    const int bn = blockIdx.x;
    const int bo = blockIdx.y;
    const int b  = blockIdx.z;
    const int t  = threadIdx.x;
    const int w  = t >> 6, l = t & 63, g = l >> 4, m = l & 15;
    const int o0 = bo * 128, n0 = bn * 128;
    const int part = o0 >> 9;    // 0=q 1=k 2=v
    const int wr = w >> 1, wc = w & 1;

    __shared__ __align__(16) ushort SH[2*128*64];
    ushort* Xs  = SH;
    ushort* Ws_ = SH + 128*64;

    const ushort* xbase = xT + ((size_t)b*NN + n0)*CC;
    const ushort* wbase = Wb + (size_t)o0*CC;

    f32x4 acc[4][4];
    #pragma unroll
    for (int i=0;i<4;i++)
        #pragma unroll
        for (int j=0;j<4;j++) acc[i][j] = (f32x4){0.f,0.f,0.f,0.f};

    const ushort* R = (part < 2) ? Xs  : Ws_;
    const ushort* Cc = (part < 2) ? Ws_ : Xs;

    for (int k0 = 0; k0 < CC; k0 += 64) {
        #pragma unroll
        for (int it = 0; it < 4; ++it) {
            int c16 = (it*4 + w)*64 + l;
            int row = c16 >> 3;
            int gch = (c16 & 7) ^ (row & 7);
            gload_lds16(xbase + (size_t)row*CC + k0 + gch*8, Xs  + c16*8);
            gload_lds16(wbase + (size_t)row*CC + k0 + gch*8, Ws_ + c16*8);
        }
        __syncthreads();
        __builtin_amdgcn_s_setprio(1);
        #pragma unroll
        for (int kc = 0; kc < 2; ++kc) {
            bfx8 ra[4], cb[4];
            #pragma unroll
            for (int f = 0; f < 4; ++f) {
                int rrow = wr*64 + f*16 + m;
                ra[f] = *(const bfx8*)(R  + (rrow*8 + ((kc*4+g) ^ (rrow&7)))*8);
                int crow = wc*64 + f*16 + m;
                cb[f] = *(const bfx8*)(Cc + (crow*8 + ((kc*4+g) ^ (crow&7)))*8);
            }
            #pragma unroll
            for (int i = 0; i < 4; ++i)
                #pragma unroll
                for (int j = 0; j < 4; ++j)
                    acc[i][j] = __builtin_amdgcn_mfma_f32_16x16x32_bf16(ra[i], cb[j], acc[i][j], 0, 0, 0);
        }
        __builtin_amdgcn_s_setprio(0);
        __syncthreads();
    }

    // ---- epilogue: bias, bf16, LDS bounce (chunk-swizzled), coalesced b128 stores ----
    // A-dim (rows): wr*64+i*16+g*4+r ; B-dim (cols): wc*64+j*16+m
    float bvj[4];        // part<2: bias indexed by B-dim (o)
    float bvi[4][4];     // part=2: bias indexed by A-dim (o)
    if (part < 2) {
        const float bs = (part == 0) ? QSCALE : 1.f;
        #pragma unroll
        for (int j = 0; j < 4; ++j) bvj[j] = bias[o0 + wc*64 + j*16 + m] * bs;
    } else {
        #pragma unroll
        for (int i = 0; i < 4; ++i) {
            const float4 bt = *(const float4*)(&bias[o0 + wr*64 + i*16 + g*4]);
            bvi[i][0]=bt.x; bvi[i][1]=bt.y; bvi[i][2]=bt.z; bvi[i][3]=bt.w;
        }
    }
    ushort* Lb = SH;   // 128 x 128 bf16, rows=A-dim, cols=B-dim, 16B-chunk ^= (row&15)
    #pragma unroll
    for (int i = 0; i < 4; ++i)
        #pragma unroll
        for (int j = 0; j < 4; ++j)
            #pragma unroll
            for (int r = 0; r < 4; ++r) {
                int A = wr*64 + i*16 + g*4 + r;
                int Bc = wc*64 + j*16 + m;
                float val = acc[i][j][r] + ((part < 2) ? bvj[j] : bvi[i][r]);
                int ch = (Bc >> 3) ^ (A & 15);
                Lb[A*128 + ch*8 + (Bc & 7)] = f2bf(val);
            }
    __syncthreads();
    {
        const int row = t >> 1, cp = t & 1;
        const int h0 = (o0 & 511) >> 6;
        ushort* dp;
        if (part < 2) {
            ushort* dst = (part == 0) ? qws : kws;
            dp = dst + (((size_t)b*NH + h0 + cp)*NN + n0 + row)*DDIM;
        } else {
            int h = h0 + (row >> 6), d = row & 63;
            dp = vws + (((size_t)b*NH + h)*DDIM + d)*NN + n0 + cp*64;
        }
        #pragma unroll
        for (int k = 0; k < 8; ++k) {
            int ch = (cp*8 + k) ^ (row & 15);
            *(float4*)(dp + k*8) = *(const float4*)(&Lb[row*128 + ch*8]);
        }
    }
}

// ---------------- Flash attention (fixed-max, key-split, gload_lds staging) ----------------
// grid.x = 64: qt = bx>>1 (128 q rows), half = bx&1 (2048 keys). Partial O/l out.
__global__ __launch_bounds__(256, 4)
void attn_mfma(const ushort* __restrict__ qw, const ushort* __restrict__ kw,
               const ushort* __restrict__ vw, const float* __restrict__ mask,
               ushort* __restrict__ opart, float* __restrict__ lpart) {
    const int qt = blockIdx.x >> 1, half = blockIdx.x & 1;
    const int h = blockIdx.y, b = blockIdx.z;
    const int t = threadIdx.x;
    const int w = t >> 6, l = t & 63, g = l >> 4, m = l & 15;
    const int n0 = qt * 128;
    const int koff0 = half * 2048;
    const size_t bh = (size_t)b * NH + h;
    const ushort* qp = qw + bh * (size_t)NN * DDIM;
    const ushort* kp = kw + bh * (size_t)NN * DDIM;
    const ushort* vp = vw + bh * (size_t)DDIM * NN;

    __shared__ __align__(16) ushort Ks[2][64*64];   // [key][d] chunk-swizzled
    __shared__ __align__(16) ushort Vs[2][64*64];   // [d][key] chunk-swizzled
    __shared__ float mb[2][64];

    // stage one 64-key tile into LDS[buf] via global_load_lds (pre-swizzled source)
    #define STAGE(buf, ko) { \
        _Pragma("unroll") \
        for (int it = 0; it < 2; ++it) { \
            int c16 = it*256 + t; \
            int row = c16 >> 3, gch = (c16 & 7) ^ (row & 7); \
            gload_lds16(kp + (size_t)((ko) + row)*DDIM + gch*8, &Ks[buf][c16*8]); \
            gload_lds16(vp + (size_t)row*NN + (ko) + gch*8, &Vs[buf][c16*8]); \
        } }

    // Q fragments (B-operand): q = n0 + w*32 + qi*16 + m
    bfx8 qf[2][2];
    #pragma unroll
    for (int qi = 0; qi < 2; ++qi)
        #pragma unroll
        for (int kc = 0; kc < 2; ++kc)
            qf[qi][kc] = *(const bfx8*)(qp + (size_t)(n0 + w*32 + qi*16 + m)*DDIM + kc*32 + g*8);

    f32x4 o[2][4];
    #pragma unroll
    for (int qi=0; qi<2; ++qi)
        #pragma unroll
        for (int f=0; f<4; ++f) o[qi][f] = (f32x4){0.f,0.f,0.f,0.f};
    float l_part[2] = {0.f, 0.f};

    // prologue: tile 0 staged; mask tile 0 -> mb[0]; mask tile 1 -> reg
    STAGE(0, koff0);
    float mreg = 0.f;
    if (t < 64) mreg = mask[(size_t)b*NN + koff0 + t];
    if (t < 64) mb[0][t] = (1.f - mreg) * MBIAS;
    if (t < 64) mreg = mask[(size_t)b*NN + koff0 + 64 + t];
    __syncthreads();

    for (int kt = 0; kt < 32; ++kt) {
        const int cur = kt & 1, nxt = cur ^ 1;
        if (kt + 1 < 32) {
            STAGE(nxt, koff0 + (kt+1)*64);
            if (t < 64) mb[nxt][t] = (1.f - mreg) * MBIAS;
            if (kt + 2 < 32 && t < 64) mreg = mask[(size_t)b*NN + koff0 + (kt+2)*64 + t];
        }

        // mask bias for this tile (keys 16f+4g+r)
        float4 mbv[4];
        #pragma unroll
        for (int f=0; f<4; ++f) mbv[f] = *(const float4*)(&mb[cur][f*16 + 4*g]);

        // ---- S^T = K Q^T, accumulator seeded with mask bias ----
        f32x4 sa[2][4];
        #pragma unroll
        for (int qi=0; qi<2; ++qi)
            #pragma unroll
            for (int f=0; f<4; ++f)
                sa[qi][f] = (f32x4){mbv[f].x, mbv[f].y, mbv[f].z, mbv[f].w};
        __builtin_amdgcn_s_setprio(1);
        #pragma unroll
        for (int kc=0; kc<2; ++kc)
            #pragma unroll
            for (int f=0; f<4; ++f) {
                int row = f*16 + m;
                bfx8 kf = *(const bfx8*)(&Ks[cur][row*64 + ((kc*32 + g*8) ^ ((row&7)*8))]);
                #pragma unroll
                for (int qi=0; qi<2; ++qi)
                    sa[qi][f] = __builtin_amdgcn_mfma_f32_16x16x32_bf16(kf, qf[qi][kc], sa[qi][f], 0, 0, 0);
            }
        __builtin_amdgcn_s_setprio(0);

        // ---- fixed-max softmax: P = exp2(S); no max tracking ----
        bfx8 pa[2][2];
        #pragma unroll
        for (int qi=0; qi<2; ++qi) {
            float pv_[4][4];
            float tsum = 0.f;
            #pragma unroll
            for (int f=0; f<4; ++f)
                #pragma unroll
                for (int r=0; r<4; ++r) {
                    float p = __builtin_amdgcn_exp2f(sa[qi][f][r]);
                    pv_[f][r] = p;
                    tsum += p;
                }
            l_part[qi] += tsum;

            int u[4][2];
            #pragma unroll
            for (int f=0; f<4; ++f)
                #pragma unroll
                for (int pp=0; pp<2; ++pp) {
                    bf2 tpk = { (__bf16)pv_[f][2*pp], (__bf16)pv_[f][2*pp+1] };
                    u[f][pp] = __builtin_bit_cast(int, tpk);
                }
            #pragma unroll
            for (int pp=0; pp<2; ++pp) { swap32(u[0][pp], u[1][pp]); swap32(u[2][pp], u[3][pp]); }
            #pragma unroll
            for (int pp=0; pp<2; ++pp) { swap16(u[0][pp], u[1][pp]); swap16(u[2][pp], u[3][pp]); }
            pa[qi][0] = __builtin_bit_cast(bfx8, (i32x4){u[0][0], u[0][1], u[1][0], u[1][1]});
            pa[qi][1] = __builtin_bit_cast(bfx8, (i32x4){u[2][0], u[2][1], u[3][0], u[3][1]});
        }

        // ---- O += P V ----
        __builtin_amdgcn_s_setprio(1);
        #pragma unroll
        for (int kc=0; kc<2; ++kc)
            #pragma unroll
            for (int f=0; f<4; ++f) {
                int row = f*16 + m;
                bfx8 vf = *(const bfx8*)(&Vs[cur][row*64 + ((kc*32 + g*8) ^ ((row&7)*8))]);
                #pragma unroll
                for (int qi=0; qi<2; ++qi)
                    o[qi][f] = __builtin_amdgcn_mfma_f32_16x16x32_bf16(pa[qi][kc], vf, o[qi][f], 0, 0, 0);
            }
        __builtin_amdgcn_s_setprio(0);
        __syncthreads();
    }

    // ---- reduce l over g-groups; store partial O (bf16) and l (f32) ----
    const size_t obase = (bh*2 + half) * (size_t)NN;
    #pragma unroll
    for (int qi=0; qi<2; ++qi) {
        float l_tot = l_part[qi] + __shfl_xor(l_part[qi], 16);
        l_tot += __shfl_xor(l_tot, 32);
        if (g == 0) lpart[obase + n0 + w*32 + qi*16 + m] = l_tot;
        #pragma unroll
        for (int f=0; f<4; ++f)
            #pragma unroll
            for (int r=0; r<4; ++r)
                opart[(obase + n0 + w*32 + qi*16 + 4*g + r)*DDIM + f*16 + m] = f2bf(o[qi][f][r]);
    }
    #undef STAGE
}

// ---------------- combine: aob = (O0+O1)/(l0+l1), bf16 [B][N][C] ----------------
__global__ __launch_bounds__(256)
void combine_k(const ushort* __restrict__ opart, const float* __restrict__ lpart,
               ushort* __restrict__ aob) {
    const int t = threadIdx.x;
    const int n = blockIdx.x*64 + (t >> 2), dq = t & 3;
    const int h = blockIdx.y, b = blockIdx.z;
    const size_t bh = (size_t)b*NH + h;
    const float linv = 1.f / (lpart[(bh*2+0)*NN + n] + lpart[(bh*2+1)*NN + n]);
    const ushort* p0 = opart + ((bh*2+0)*(size_t)NN + n)*DDIM + dq*16;
    const ushort* p1 = opart + ((bh*2+1)*(size_t)NN + n)*DDIM + dq*16;
    ushort* dst = aob + ((size_t)b*NN + n)*CC + h*DDIM + dq*16;
    #pragma unroll
    for (int c = 0; c < 2; ++c) {
        usx8 u0 = *(const usx8*)(p0 + c*8);
        usx8 u1 = *(const usx8*)(p1 + c*8);
        usx8 res;
        #pragma unroll
        for (int j = 0; j < 8; ++j)
            res[j] = f2bf((bf2f(u0[j]) + bf2f(u1[j])) * linv);
        *(usx8*)(dst + c*8) = res;
    }
}

// ---------------- Proj GEMM (bf16 MFMA, fp32 out) ----------------
__global__ __launch_bounds__(256)
void proj_mfma(const ushort* __restrict__ aob, const ushort* __restrict__ Wp,
               const float* __restrict__ bias, float* __restrict__ out) {
    const int bn = blockIdx.x;
    const int bo = blockIdx.y;
    const int b  = blockIdx.z;
    const int t  = threadIdx.x;
    const int w  = t >> 6, l = t & 63, g = l >> 4, m = l & 15;
    const int o0 = bo * 128, n0 = bn * 128;
    const int wr = w >> 1, wc = w & 1;

    __shared__ __align__(16) ushort As_[128*64];
    __shared__ __align__(16) ushort Ws_[128*64];

    const ushort* abase = aob + ((size_t)b*NN + n0)*CC;
    const ushort* wbase = Wp + (size_t)o0*CC;

    f32x4 acc[4][4];
    #pragma unroll
    for (int i=0;i<4;i++)
        #pragma unroll
        for (int j=0;j<4;j++) acc[i][j] = (f32x4){0.f,0.f,0.f,0.f};

    for (int k0 = 0; k0 < CC; k0 += 64) {
        #pragma unroll
        for (int it = 0; it < 4; ++it) {
            int c16 = (it*4 + w)*64 + l;
            int row = c16 >> 3;
            int gch = (c16 & 7) ^ (row & 7);
            gload_lds16(abase + (size_t)row*CC + k0 + gch*8, As_ + c16*8);
            gload_lds16(wbase + (size_t)row*CC + k0 + gch*8, Ws_ + c16*8);
        }
        __syncthreads();
        __builtin_amdgcn_s_setprio(1);
        #pragma unroll
        for (int kc = 0; kc < 2; ++kc) {
            bfx8 ra[4], cb[4];
            #pragma unroll
            for (int f = 0; f < 4; ++f) {
                int rrow = wr*64 + f*16 + m;
                ra[f] = *(const bfx8*)(Ws_ + (rrow*8 + ((kc*4+g) ^ (rrow&7)))*8);
                int crow = wc*64 + f*16 + m;
                cb[f] = *(const bfx8*)(As_ + (crow*8 + ((kc*4+g) ^ (crow&7)))*8);
            }
            #pragma unroll
            for (int i = 0; i < 4; ++i)
                #pragma unroll
                for (int j = 0; j < 4; ++j)
                    acc[i][j] = __builtin_amdgcn_mfma_f32_16x16x32_bf16(ra[i], cb[j], acc[i][j], 0, 0, 0);
        }
        __builtin_amdgcn_s_setprio(0);
        __syncthreads();
    }
    #pragma unroll
    for (int i = 0; i < 4; ++i)
        #pragma unroll
        for (int r = 0; r < 4; ++r) {
            int o = o0 + wr*64 + i*16 + g*4 + r;
            float bv = bias[o];
            float* dp = out + ((size_t)b*CC + o)*NN;
            #pragma unroll
            for (int j = 0; j < 4; ++j) {
                int n = n0 + wc*64 + j*16 + m;
                dp[n] = acc[i][j][r] + bv;
            }
        }
}

extern "C" void kernel_launch(void* const* d_in, const int* in_sizes, int n_in,
                              void* d_out, int out_size, void* d_ws, size_t ws_size,
                              hipStream_t stream) {
    const float* x     = (const float*)d_in[0];
    const float* mask  = (const float*)d_in[1];
    const float* Wqkv  = (const float*)d_in[2];
    const float* bqkv  = (const float*)d_in[3];
    const float* Wproj = (const float*)d_in[4];
    const float* bproj = (const float*)d_in[5];
    float* out = (float*)d_out;

    const size_t per = (size_t)BB*NH*NN*DDIM;    // 4,194,304 elems
    ushort* qws = (ushort*)d_ws;
    ushort* kws = qws + per;
    ushort* vws = kws + per;
    ushort* xTb = vws + per;
    ushort* aob = xTb + per;
    ushort* Wqb = aob + per;
    ushort* Wpb = Wqb + (size_t)1536*CC;
    ushort* opart = Wpb + (size_t)CC*CC;         // [B][NH][2][N][64] bf16 (16 MB)
    float*  lpart = (float*)(opart + 2*per);     // [B][NH][2][N] f32 (512 KB)

    convert_w<<<dim3(1024), 256, 0, stream>>>(Wqkv, Wproj, Wqb, Wpb);
    transpose_x<<<dim3(64, 8, BB), 256, 0, stream>>>(x, xTb);
    qkv_mfma<<<dim3(32, 12, BB), 256, 0, stream>>>(xTb, Wqb, bqkv, qws, kws, vws);
    attn_mfma<<<dim3(64, NH, BB), 256, 0, stream>>>(qws, kws, vws, mask, opart, lpart);
    combine_k<<<dim3(64, NH, BB), 256, 0, stream>>>(opart, lpart, aob);
    proj_mfma<<<dim3(32, 4, BB), 256, 0, stream>>>(aob, Wpb, bproj, out);
}

// Round 7
// 196.588 us; speedup vs baseline: 11.2868x; 1.0261x over previous
//
#include <hip/hip_runtime.h>

#define BB 2
#define CC 512
#define NH 8
#define DDIM 64
#define NN 4096
// 0.125 * log2(e) folded into Wq; exp computed as 2^x
#define QSCALE 0.18033688011112042f
#define MBIAS  -14426.950408889634f

typedef __bf16 bfx8 __attribute__((ext_vector_type(8)));
typedef __bf16 bf2  __attribute__((ext_vector_type(2)));
typedef float  f32x4 __attribute__((ext_vector_type(4)));
typedef int    i32x4 __attribute__((ext_vector_type(4)));
typedef ushort usx8  __attribute__((ext_vector_type(8)));

__device__ inline ushort f2bf(float f) {
  return __builtin_bit_cast(ushort, (__bf16)f);
}
__device__ inline float bf2f(ushort u) {
  return (float)__builtin_bit_cast(__bf16, u);
}

__device__ __forceinline__ void gload_lds16(const void* g, void* l) {
  __builtin_amdgcn_global_load_lds(
      (const __attribute__((address_space(1))) void*)g,
      (__attribute__((address_space(3))) void*)l, 16, 0, 0);
}

__device__ __forceinline__ void swap32(int& a, int& b) {
  asm("v_permlane32_swap_b32 %0, %1" : "+v"(a), "+v"(b));
}
__device__ __forceinline__ void swap16(int& a, int& b) {
  asm("v_permlane16_swap_b32 %0, %1" : "+v"(a), "+v"(b));
}

// ------- weight convert fp32 -> bf16 (Q pre-scaled) + mask-bias precompute -------
__global__ __launch_bounds__(256)
void convert_w(const float* __restrict__ Wqkv, const float* __restrict__ Wproj,
               const float* __restrict__ mask,
               ushort* __restrict__ Wq, ushort* __restrict__ Wp,
               float* __restrict__ mbias) {
    const int n1 = (1536*CC)/4;
    const int n2 = (CC*CC)/4;
    const int n3 = (BB*NN)/4;
    int i = blockIdx.x*256 + threadIdx.x;
    if (i < n1) {
        float4 v = *(const float4*)(&Wqkv[(size_t)i*4]);
        if (i < 65536) { v.x*=QSCALE; v.y*=QSCALE; v.z*=QSCALE; v.w*=QSCALE; }
        ushort4 o; o.x=f2bf(v.x); o.y=f2bf(v.y); o.z=f2bf(v.z); o.w=f2bf(v.w);
        *(ushort4*)(&Wq[(size_t)i*4]) = o;
    } else if (i < n1+n2) {
        int j = i - n1;
        float4 v = *(const float4*)(&Wproj[(size_t)j*4]);
        ushort4 o; o.x=f2bf(v.x); o.y=f2bf(v.y); o.z=f2bf(v.z); o.w=f2bf(v.w);
        *(ushort4*)(&Wp[(size_t)j*4]) = o;
    } else if (i < n1+n2+n3) {
        int j = i - n1 - n2;
        float4 mv = *(const float4*)(&mask[(size_t)j*4]);
        float4 ob;
        ob.x = (1.f - mv.x) * MBIAS; ob.y = (1.f - mv.y) * MBIAS;
        ob.z = (1.f - mv.z) * MBIAS; ob.w = (1.f - mv.w) * MBIAS;
        *(float4*)(&mbias[(size_t)j*4]) = ob;
    }
}

// ---------------- transpose x [B][C][N] f32 -> xT [B][N][C] bf16 ----------------
__global__ __launch_bounds__(256)
void transpose_x(const float* __restrict__ x, ushort* __restrict__ xT) {
    const int bn = blockIdx.x, bc = blockIdx.y, b = blockIdx.z;
    const int t = threadIdx.x;
    __shared__ float T[64][65];
    const int n0 = bn*64, c0 = bc*64;
    const int tc = t >> 4, tn4 = (t & 15) * 4;
    #pragma unroll
    for (int r = 0; r < 4; ++r) {
        int c = tc + r*16;
        float4 v = *(const float4*)(&x[((size_t)b*CC + c0 + c)*NN + n0 + tn4]);
        T[c][tn4+0] = v.x; T[c][tn4+1] = v.y; T[c][tn4+2] = v.z; T[c][tn4+3] = v.w;
    }
    __syncthreads();
    #pragma unroll
    for (int r = 0; r < 4; ++r) {
        int n = tc + r*16;
        ushort4 o;
        o.x = f2bf(T[tn4+0][n]); o.y = f2bf(T[tn4+1][n]);
        o.z = f2bf(T[tn4+2][n]); o.w = f2bf(T[tn4+3][n]);
        *(ushort4*)(&xT[((size_t)b*NN + n0 + n)*CC + c0 + tn4]) = o;
    }
}

// ---------------- QKV GEMM (bf16 MFMA, 2-phase dbuf, LDS-bounce epilogue) ----------------
__global__ __launch_bounds__(256)
void qkv_mfma(const ushort* __restrict__ xT, const ushort* __restrict__ Wb,
              const float* __restrict__ bias, ushort* __restrict__ qws,
              ushort* __restrict__ kws, ushort* __restrict__ vws) {
    // XCD-bijective swizzle (768 blocks, 768%8==0)
    const int wg = (blockIdx.x & 7) * 96 + (blockIdx.x >> 3);
    const int bn = wg & 31;
    const int bo = (wg % 384) / 32;
    const int b  = wg / 384;
    const int t  = threadIdx.x;
    const int w  = t >> 6, l = t & 63, g = l >> 4, m = l & 15;
    const int o0 = bo * 128, n0 = bn * 128;
    const int part = o0 >> 9;    // 0=q 1=k 2=v
    const int wr = w >> 1, wc = w & 1;

    __shared__ __align__(16) ushort SH[4*128*64];   // Xs[2] | Ws[2], 64 KB

    const ushort* xbase = xT + ((size_t)b*NN + n0)*CC;
    const ushort* wbase = Wb + (size_t)o0*CC;

    f32x4 acc[4][4];
    #pragma unroll
    for (int i=0;i<4;i++)
        #pragma unroll
        for (int j=0;j<4;j++) acc[i][j] = (f32x4){0.f,0.f,0.f,0.f};

    #define QSTAGE(buf, k0) { \
        _Pragma("unroll") \
        for (int it = 0; it < 4; ++it) { \
            int c16 = (it*4 + w)*64 + l; \
            int row = c16 >> 3; \
            int gch = (c16 & 7) ^ (row & 7); \
            gload_lds16(xbase + (size_t)row*CC + (k0) + gch*8, SH + (buf)*8192 + c16*8); \
            gload_lds16(wbase + (size_t)row*CC + (k0) + gch*8, SH + 16384 + (buf)*8192 + c16*8); \
        } }

    QSTAGE(0, 0);
    __syncthreads();

    for (int k0i = 0; k0i < 8; ++k0i) {
        const int cur = k0i & 1, nxt = cur ^ 1;
        if (k0i + 1 < 8) QSTAGE(nxt, (k0i+1)*64);

        const ushort* Xs  = SH + cur*8192;
        const ushort* Ws_ = SH + 16384 + cur*8192;
        const ushort* R  = (part < 2) ? Xs  : Ws_;
        const ushort* Cc = (part < 2) ? Ws_ : Xs;

        __builtin_amdgcn_s_setprio(1);
        #pragma unroll
        for (int kc = 0; kc < 2; ++kc) {
            bfx8 ra[4], cb[4];
            #pragma unroll
            for (int f = 0; f < 4; ++f) {
                int rrow = wr*64 + f*16 + m;
                ra[f] = *(const bfx8*)(R  + (rrow*8 + ((kc*4+g) ^ (rrow&7)))*8);
                int crow = wc*64 + f*16 + m;
                cb[f] = *(const bfx8*)(Cc + (crow*8 + ((kc*4+g) ^ (crow&7)))*8);
            }
            #pragma unroll
            for (int i = 0; i < 4; ++i)
                #pragma unroll
                for (int j = 0; j < 4; ++j)
                    acc[i][j] = __builtin_amdgcn_mfma_f32_16x16x32_bf16(ra[i], cb[j], acc[i][j], 0, 0, 0);
        }
        __builtin_amdgcn_s_setprio(0);
        __syncthreads();
    }
    #undef QSTAGE

    // ---- epilogue: bias, bf16, LDS bounce (chunk-swizzled), coalesced b128 stores ----
    float bvj[4];
    float bvi[4][4];
    if (part < 2) {
        const float bs = (part == 0) ? QSCALE : 1.f;
        #pragma unroll
        for (int j = 0; j < 4; ++j) bvj[j] = bias[o0 + wc*64 + j*16 + m] * bs;
    } else {
        #pragma unroll
        for (int i = 0; i < 4; ++i) {
            const float4 bt = *(const float4*)(&bias[o0 + wr*64 + i*16 + g*4]);
            bvi[i][0]=bt.x; bvi[i][1]=bt.y; bvi[i][2]=bt.z; bvi[i][3]=bt.w;
        }
    }
    ushort* Lb = SH;   // 128 x 128 bf16, 16B-chunk ^= (row&15)
    #pragma unroll
    for (int i = 0; i < 4; ++i)
        #pragma unroll
        for (int j = 0; j < 4; ++j)
            #pragma unroll
            for (int r = 0; r < 4; ++r) {
                int A = wr*64 + i*16 + g*4 + r;
                int Bc = wc*64 + j*16 + m;
                float val = acc[i][j][r] + ((part < 2) ? bvj[j] : bvi[i][r]);
                int ch = (Bc >> 3) ^ (A & 15);
                Lb[A*128 + ch*8 + (Bc & 7)] = f2bf(val);
            }
    __syncthreads();
    {
        const int row = t >> 1, cp = t & 1;
        const int h0 = (o0 & 511) >> 6;
        ushort* dp;
        if (part < 2) {
            ushort* dst = (part == 0) ? qws : kws;
            dp = dst + (((size_t)b*NH + h0 + cp)*NN + n0 + row)*DDIM;
        } else {
            int h = h0 + (row >> 6), d = row & 63;
            dp = vws + (((size_t)b*NH + h)*DDIM + d)*NN + n0 + cp*64;
        }
        #pragma unroll
        for (int k = 0; k < 8; ++k) {
            int ch = (cp*8 + k) ^ (row & 15);
            *(float4*)(dp + k*8) = *(const float4*)(&Lb[row*128 + ch*8]);
        }
    }
}

// ------- Flash attention (fixed-max, key-split, l-via-ones-MFMA, XCD swizzle) -------
// flat grid 1024: per (b,h): 32 qt x 2 half. Partial O/l out.
__global__ __launch_bounds__(256, 4)
void attn_mfma(const ushort* __restrict__ qw, const ushort* __restrict__ kw,
               const ushort* __restrict__ vw, const float* __restrict__ mbias,
               ushort* __restrict__ opart, float* __restrict__ lpart) {
    const int wg = (blockIdx.x & 7) * 128 + (blockIdx.x >> 3);
    const int qt = (wg & 63) >> 1, half = wg & 1;
    const int h = (wg >> 6) & 7, b = wg >> 9;
    const int t = threadIdx.x;
    const int w = t >> 6, l = t & 63, g = l >> 4, m = l & 15;
    const int n0 = qt * 128;
    const int koff0 = half * 2048;
    const size_t bh = (size_t)b * NH + h;
    const ushort* qp = qw + bh * (size_t)NN * DDIM;
    const ushort* kp = kw + bh * (size_t)NN * DDIM;
    const ushort* vp = vw + bh * (size_t)DDIM * NN;
    const float*  mbp = mbias + (size_t)b*NN + koff0;

    __shared__ __align__(16) ushort Ks[2][64*64];   // [key][d] chunk-swizzled
    __shared__ __align__(16) ushort Vs[2][64*64];   // [d][key] chunk-swizzled

    #define STAGE(buf, ko) { \
        _Pragma("unroll") \
        for (int it = 0; it < 2; ++it) { \
            int c16 = it*256 + t; \
            int row = c16 >> 3, gch = (c16 & 7) ^ (row & 7); \
            gload_lds16(kp + (size_t)((ko) + row)*DDIM + gch*8, &Ks[buf][c16*8]); \
            gload_lds16(vp + (size_t)row*NN + (ko) + gch*8, &Vs[buf][c16*8]); \
        } }

    bfx8 qf[2][2];
    #pragma unroll
    for (int qi = 0; qi < 2; ++qi)
        #pragma unroll
        for (int kc = 0; kc < 2; ++kc)
            qf[qi][kc] = *(const bfx8*)(qp + (size_t)(n0 + w*32 + qi*16 + m)*DDIM + kc*32 + g*8);

    f32x4 o[2][4];
    #pragma unroll
    for (int qi=0; qi<2; ++qi)
        #pragma unroll
        for (int f=0; f<4; ++f) o[qi][f] = (f32x4){0.f,0.f,0.f,0.f};
    f32x4 lacc[2];
    lacc[0] = (f32x4){0.f,0.f,0.f,0.f};
    lacc[1] = (f32x4){0.f,0.f,0.f,0.f};
    const bfx8 vones = {(__bf16)1.f,(__bf16)1.f,(__bf16)1.f,(__bf16)1.f,
                        (__bf16)1.f,(__bf16)1.f,(__bf16)1.f,(__bf16)1.f};

    STAGE(0, koff0);
    __syncthreads();

    for (int kt = 0; kt < 32; ++kt) {
        const int cur = kt & 1, nxt = cur ^ 1;

        // mask-bias loads FIRST (so their waitcnt doesn't drain the stage queue)
        float4 mb4[4];
        #pragma unroll
        for (int f=0; f<4; ++f)
            mb4[f] = *(const float4*)(mbp + kt*64 + f*16 + 4*g);

        if (kt + 1 < 32) STAGE(nxt, koff0 + (kt+1)*64);

        // ---- S^T = K Q^T, accumulator seeded with mask bias ----
        f32x4 sa[2][4];
        #pragma unroll
        for (int qi=0; qi<2; ++qi)
            #pragma unroll
            for (int f=0; f<4; ++f)
                sa[qi][f] = __builtin_bit_cast(f32x4, mb4[f]);
        __builtin_amdgcn_s_setprio(1);
        #pragma unroll
        for (int kc=0; kc<2; ++kc)
            #pragma unroll
            for (int f=0; f<4; ++f) {
                int row = f*16 + m;
                bfx8 kf = *(const bfx8*)(&Ks[cur][row*64 + ((kc*32 + g*8) ^ ((row&7)*8))]);
                #pragma unroll
                for (int qi=0; qi<2; ++qi)
                    sa[qi][f] = __builtin_amdgcn_mfma_f32_16x16x32_bf16(kf, qf[qi][kc], sa[qi][f], 0, 0, 0);
            }
        __builtin_amdgcn_s_setprio(0);

        // ---- fixed-max softmax: P = exp2(S) ----
        bfx8 pa[2][2];
        #pragma unroll
        for (int qi=0; qi<2; ++qi) {
            float pv_[4][4];
            #pragma unroll
            for (int f=0; f<4; ++f)
                #pragma unroll
                for (int r=0; r<4; ++r)
                    pv_[f][r] = __builtin_amdgcn_exp2f(sa[qi][f][r]);

            int u[4][2];
            #pragma unroll
            for (int f=0; f<4; ++f)
                #pragma unroll
                for (int pp=0; pp<2; ++pp) {
                    bf2 tpk = { (__bf16)pv_[f][2*pp], (__bf16)pv_[f][2*pp+1] };
                    u[f][pp] = __builtin_bit_cast(int, tpk);
                }
            #pragma unroll
            for (int pp=0; pp<2; ++pp) { swap32(u[0][pp], u[1][pp]); swap32(u[2][pp], u[3][pp]); }
            #pragma unroll
            for (int pp=0; pp<2; ++pp) { swap16(u[0][pp], u[1][pp]); swap16(u[2][pp], u[3][pp]); }
            pa[qi][0] = __builtin_bit_cast(bfx8, (i32x4){u[0][0], u[0][1], u[1][0], u[1][1]});
            pa[qi][1] = __builtin_bit_cast(bfx8, (i32x4){u[2][0], u[2][1], u[3][0], u[3][1]});
        }

        // ---- O += P V ; l += P 1 (ones-MFMA) ----
        __builtin_amdgcn_s_setprio(1);
        #pragma unroll
        for (int kc=0; kc<2; ++kc) {
            #pragma unroll
            for (int f=0; f<4; ++f) {
                int row = f*16 + m;
                bfx8 vf = *(const bfx8*)(&Vs[cur][row*64 + ((kc*32 + g*8) ^ ((row&7)*8))]);
                #pragma unroll
                for (int qi=0; qi<2; ++qi)
                    o[qi][f] = __builtin_amdgcn_mfma_f32_16x16x32_bf16(pa[qi][kc], vf, o[qi][f], 0, 0, 0);
            }
            #pragma unroll
            for (int qi=0; qi<2; ++qi)
                lacc[qi] = __builtin_amdgcn_mfma_f32_16x16x32_bf16(pa[qi][kc], vones, lacc[qi], 0, 0, 0);
        }
        __builtin_amdgcn_s_setprio(0);
        __syncthreads();
    }
    #undef STAGE

    // ---- store partial O (bf16) and l (f32; lacc[r] = l[q=4g+r], uniform over m) ----
    const size_t obase = (bh*2 + half) * (size_t)NN;
    #pragma unroll
    for (int qi=0; qi<2; ++qi) {
        if (m == 0) {
            #pragma unroll
            for (int r=0; r<4; ++r)
                lpart[obase + n0 + w*32 + qi*16 + 4*g + r] = lacc[qi][r];
        }
        #pragma unroll
        for (int f=0; f<4; ++f)
            #pragma unroll
            for (int r=0; r<4; ++r)
                opart[(obase + n0 + w*32 + qi*16 + 4*g + r)*DDIM + f*16 + m] = f2bf(o[qi][f][r]);
    }
}

// ---------------- combine: aob = (O0+O1)/(l0+l1), bf16 [B][N][C] ----------------
__global__ __launch_bounds__(256)
void combine_k(const ushort* __restrict__ opart, const float* __restrict__ lpart,
               ushort* __restrict__ aob) {
    const int t = threadIdx.x;
    const int n = blockIdx.x*64 + (t >> 2), dq = t & 3;
    const int h = blockIdx.y, b = blockIdx.z;
    const size_t bh = (size_t)b*NH + h;
    const float linv = 1.f / (lpart[(bh*2+0)*NN + n] + lpart[(bh*2+1)*NN + n]);
    const ushort* p0 = opart + ((bh*2+0)*(size_t)NN + n)*DDIM + dq*16;
    const ushort* p1 = opart + ((bh*2+1)*(size_t)NN + n)*DDIM + dq*16;
    ushort* dst = aob + ((size_t)b*NN + n)*CC + h*DDIM + dq*16;
    #pragma unroll
    for (int c = 0; c < 2; ++c) {
        usx8 u0 = *(const usx8*)(p0 + c*8);
        usx8 u1 = *(const usx8*)(p1 + c*8);
        usx8 res;
        #pragma unroll
        for (int j = 0; j < 8; ++j)
            res[j] = f2bf((bf2f(u0[j]) + bf2f(u1[j])) * linv);
        *(usx8*)(dst + c*8) = res;
    }
}

// ---------------- Proj GEMM (bf16 MFMA, 2-phase dbuf, fp32 out) ----------------
__global__ __launch_bounds__(256)
void proj_mfma(const ushort* __restrict__ aob, const ushort* __restrict__ Wp,
               const float* __restrict__ bias, float* __restrict__ out) {
    // XCD-bijective swizzle (256 blocks)
    const int wg = (blockIdx.x & 7) * 32 + (blockIdx.x >> 3);
    const int bn = wg & 31;
    const int bo = (wg >> 5) & 3;
    const int b  = wg >> 7;
    const int t  = threadIdx.x;
    const int w  = t >> 6, l = t & 63, g = l >> 4, m = l & 15;
    const int o0 = bo * 128, n0 = bn * 128;
    const int wr = w >> 1, wc = w & 1;

    __shared__ __align__(16) ushort SH[4*128*64];   // As[2] | Ws[2], 64 KB

    const ushort* abase = aob + ((size_t)b*NN + n0)*CC;
    const ushort* wbase = Wp + (size_t)o0*CC;

    f32x4 acc[4][4];
    #pragma unroll
    for (int i=0;i<4;i++)
        #pragma unroll
        for (int j=0;j<4;j++) acc[i][j] = (f32x4){0.f,0.f,0.f,0.f};

    #define PSTAGE(buf, k0) { \
        _Pragma("unroll") \
        for (int it = 0; it < 4; ++it) { \
            int c16 = (it*4 + w)*64 + l; \
            int row = c16 >> 3; \
            int gch = (c16 & 7) ^ (row & 7); \
            gload_lds16(abase + (size_t)row*CC + (k0) + gch*8, SH + (buf)*8192 + c16*8); \
            gload_lds16(wbase + (size_t)row*CC + (k0) + gch*8, SH + 16384 + (buf)*8192 + c16*8); \
        } }

    PSTAGE(0, 0);
    __syncthreads();

    for (int k0i = 0; k0i < 8; ++k0i) {
        const int cur = k0i & 1, nxt = cur ^ 1;
        if (k0i + 1 < 8) PSTAGE(nxt, (k0i+1)*64);

        const ushort* As_ = SH + cur*8192;
        const ushort* Ws_ = SH + 16384 + cur*8192;

        __builtin_amdgcn_s_setprio(1);
        #pragma unroll
        for (int kc = 0; kc < 2; ++kc) {
            bfx8 ra[4], cb[4];
            #pragma unroll
            for (int f = 0; f < 4; ++f) {
                int rrow = wr*64 + f*16 + m;
                ra[f] = *(const bfx8*)(Ws_ + (rrow*8 + ((kc*4+g) ^ (rrow&7)))*8);
                int crow = wc*64 + f*16 + m;
                cb[f] = *(const bfx8*)(As_ + (crow*8 + ((kc*4+g) ^ (crow&7)))*8);
            }
            #pragma unroll
            for (int i = 0; i < 4; ++i)
                #pragma unroll
                for (int j = 0; j < 4; ++j)
                    acc[i][j] = __builtin_amdgcn_mfma_f32_16x16x32_bf16(ra[i], cb[j], acc[i][j], 0, 0, 0);
        }
        __builtin_amdgcn_s_setprio(0);
        __syncthreads();
    }
    #undef PSTAGE

    #pragma unroll
    for (int i = 0; i < 4; ++i)
        #pragma unroll
        for (int r = 0; r < 4; ++r) {
            int o = o0 + wr*64 + i*16 + g*4 + r;
            float bv = bias[o];
            float* dp = out + ((size_t)b*CC + o)*NN;
            #pragma unroll
            for (int j = 0; j < 4; ++j) {
                int n = n0 + wc*64 + j*16 + m;
                dp[n] = acc[i][j][r] + bv;
            }
        }
}

extern "C" void kernel_launch(void* const* d_in, const int* in_sizes, int n_in,
                              void* d_out, int out_size, void* d_ws, size_t ws_size,
                              hipStream_t stream) {
    const float* x     = (const float*)d_in[0];
    const float* mask  = (const float*)d_in[1];
    const float* Wqkv  = (const float*)d_in[2];
    const float* bqkv  = (const float*)d_in[3];
    const float* Wproj = (const float*)d_in[4];
    const float* bproj = (const float*)d_in[5];
    float* out = (float*)d_out;

    const size_t per = (size_t)BB*NH*NN*DDIM;    // 4,194,304 elems
    ushort* qws = (ushort*)d_ws;
    ushort* kws = qws + per;
    ushort* vws = kws + per;
    ushort* xTb = vws + per;
    ushort* aob = xTb + per;
    ushort* Wqb = aob + per;
    ushort* Wpb = Wqb + (size_t)1536*CC;
    ushort* opart = Wpb + (size_t)CC*CC;         // [B][NH][2][N][64] bf16 (16 MB)
    float*  lpart = (float*)(opart + 2*per);     // [B][NH][2][N] f32 (512 KB)
    float*  mbias = lpart + (size_t)BB*NH*2*NN;  // [B][N] f32 (32 KB)

    convert_w<<<dim3(1032), 256, 0, stream>>>(Wqkv, Wproj, mask, Wqb, Wpb, mbias);
    transpose_x<<<dim3(64, 8, BB), 256, 0, stream>>>(x, xTb);
    qkv_mfma<<<dim3(768), 256, 0, stream>>>(xTb, Wqb, bqkv, qws, kws, vws);
    attn_mfma<<<dim3(1024), 256, 0, stream>>>(qws, kws, vws, mbias, opart, lpart);
    combine_k<<<dim3(64, NH, BB), 256, 0, stream>>>(opart, lpart, aob);
    proj_mfma<<<dim3(256), 256, 0, stream>>>(aob, Wpb, bproj, out);
}